// Round 1
// baseline (4048.836 us; speedup 1.0000x reference)
//
#include <hip/hip_runtime.h>
#include <math.h>

#define DIM   1024
#define SEQT  2048
#define NB    4
#define SCALE 0.03125f   // 1/32 = DIM^-0.5, exact power of two
#define KTOP  64

// ---------------------------------------------------------------------------
// Kernel 1: y_sem = SCALE * hs @ W   -> written to d_out (staging buffer)
// M = NB*SEQT = 8192, N = K = 1024. 64x64 tile, BK=16, 256 threads, 4x4 micro.
// ---------------------------------------------------------------------------
__global__ __launch_bounds__(256) void ysem_gemm(const float* __restrict__ A,
                                                 const float* __restrict__ W,
                                                 float* __restrict__ C) {
    __shared__ float As[16][68];   // [k][row], 68-stride: 16B-aligned rows
    __shared__ float Bs[16][68];   // [k][col]

    const int tid = threadIdx.x;
    const int tx = tid & 15, ty = tid >> 4;
    const int n0 = blockIdx.x * 64;
    const int m0 = blockIdx.y * 64;

    const int arow = tid >> 2;          // 0..63
    const int ak   = (tid & 3) * 4;     // 0,4,8,12
    const int bk   = tid >> 4;          // 0..15
    const int bn   = (tid & 15) * 4;    // 0..60

    float acc[4][4] = {};

    for (int k0 = 0; k0 < DIM; k0 += 16) {
        float4 av = *reinterpret_cast<const float4*>(&A[(size_t)(m0 + arow) * DIM + k0 + ak]);
        float4 bv = *reinterpret_cast<const float4*>(&W[(size_t)(k0 + bk) * DIM + n0 + bn]);
        As[ak + 0][arow] = av.x;
        As[ak + 1][arow] = av.y;
        As[ak + 2][arow] = av.z;
        As[ak + 3][arow] = av.w;
        *reinterpret_cast<float4*>(&Bs[bk][bn]) = bv;
        __syncthreads();
#pragma unroll
        for (int k = 0; k < 16; ++k) {
            float4 a4 = *reinterpret_cast<const float4*>(&As[k][ty * 4]);
            float4 b4 = *reinterpret_cast<const float4*>(&Bs[k][tx * 4]);
            float ar[4] = {a4.x, a4.y, a4.z, a4.w};
            float br[4] = {b4.x, b4.y, b4.z, b4.w};
#pragma unroll
            for (int i = 0; i < 4; ++i)
#pragma unroll
                for (int j = 0; j < 4; ++j)
                    acc[i][j] += ar[i] * br[j];
        }
        __syncthreads();
    }
#pragma unroll
    for (int i = 0; i < 4; ++i) {
        float4 o;
        o.x = acc[i][0] * SCALE;
        o.y = acc[i][1] * SCALE;
        o.z = acc[i][2] * SCALE;
        o.w = acc[i][3] * SCALE;
        *reinterpret_cast<float4*>(&C[(size_t)(m0 + ty * 4 + i) * DIM + n0 + tx * 4]) = o;
    }
}

// ---------------------------------------------------------------------------
// Kernel 2: per 32-query tile: causal scores -> running top-64 -> y_episodic
//           gather -> gate -> final output (overwrites the y_sem row in io).
// Grid: NB * (SEQT/32) = 256 blocks, 256 threads.
// ---------------------------------------------------------------------------
__global__ __launch_bounds__(256) void topk_attn(const float* __restrict__ hs,
                                                 float* __restrict__ io) {
    const int b  = blockIdx.x >> 6;
    const int qt = 63 - (blockIdx.x & 63);   // heavy tiles first (tail hint)
    const int q0 = qt * 32;
    const float* hb = hs + (size_t)b * SEQT * DIM;

    __shared__ float Qs[32][68];     // pre-scaled by SCALE (exact pow2)
    __shared__ float Ks[32][68];
    __shared__ float sc[32][33];     // scores; stride 33 -> conflict-free scans
    __shared__ float topv[32][65];   // stride 65 -> conflict-free scans
    __shared__ int   topi[32][65];
    __shared__ float minv[32];
    __shared__ int   mpos[32];
    __shared__ int   cnt[32];
    __shared__ float red[4];
    __shared__ float gateS;

    const int tid = threadIdx.x;
    const int tx = tid & 15, ty = tid >> 4;   // score micro-tile 2x2
    const int lrow = tid >> 3;                // staging: 0..31
    const int lcol = (tid & 7) * 8;           // staging: 0..56

    if (tid < 32) { cnt[tid] = 0; minv[tid] = -INFINITY; mpos[tid] = 0; }
    __syncthreads();

    for (int jt = 0; jt <= qt; ++jt) {
        const int j0 = jt * 32;
        float a00 = 0.f, a01 = 0.f, a10 = 0.f, a11 = 0.f;

        for (int d0 = 0; d0 < DIM; d0 += 64) {
            // stage Q (scaled) and K tiles: 32 rows x 64 cols each
            {
                const float4* qsrc =
                    reinterpret_cast<const float4*>(&hb[(size_t)(q0 + lrow) * DIM + d0 + lcol]);
                float4 v0 = qsrc[0], v1 = qsrc[1];
                float4 s0 = {v0.x * SCALE, v0.y * SCALE, v0.z * SCALE, v0.w * SCALE};
                float4 s1 = {v1.x * SCALE, v1.y * SCALE, v1.z * SCALE, v1.w * SCALE};
                *reinterpret_cast<float4*>(&Qs[lrow][lcol])     = s0;
                *reinterpret_cast<float4*>(&Qs[lrow][lcol + 4]) = s1;
                const float4* ksrc =
                    reinterpret_cast<const float4*>(&hb[(size_t)(j0 + lrow) * DIM + d0 + lcol]);
                float4 w0 = ksrc[0], w1 = ksrc[1];
                *reinterpret_cast<float4*>(&Ks[lrow][lcol])     = w0;
                *reinterpret_cast<float4*>(&Ks[lrow][lcol + 4]) = w1;
            }
            __syncthreads();
#pragma unroll
            for (int d = 0; d < 64; d += 4) {
                float4 qa = *reinterpret_cast<const float4*>(&Qs[2 * ty][d]);
                float4 qb = *reinterpret_cast<const float4*>(&Qs[2 * ty + 1][d]);
                float4 ka = *reinterpret_cast<const float4*>(&Ks[2 * tx][d]);
                float4 kb = *reinterpret_cast<const float4*>(&Ks[2 * tx + 1][d]);
                a00 += qa.x * ka.x + qa.y * ka.y + qa.z * ka.z + qa.w * ka.w;
                a01 += qa.x * kb.x + qa.y * kb.y + qa.z * kb.z + qa.w * kb.w;
                a10 += qb.x * ka.x + qb.y * ka.y + qb.z * ka.z + qb.w * ka.w;
                a11 += qb.x * kb.x + qb.y * kb.y + qb.z * kb.z + qb.w * kb.w;
            }
            __syncthreads();
        }

        sc[2 * ty][2 * tx]         = a00;
        sc[2 * ty][2 * tx + 1]     = a01;
        sc[2 * ty + 1][2 * tx]     = a10;
        sc[2 * ty + 1][2 * tx + 1] = a11;
        __syncthreads();

        // top-64 merge: one thread per query row
        if (tid < 32) {
            const int q = tid;
            const int iq = q0 + q;                 // global query index
            int jmax = iq - j0;                    // candidates: j < iq
            if (jmax > 32) jmax = 32;
            int   c  = cnt[q];
            float mv = minv[q];
            int   mp = mpos[q];
            for (int jj = 0; jj < jmax; ++jj) {
                float v = sc[q][jj];
                if (c < KTOP) {
                    topv[q][c] = v;
                    topi[q][c] = j0 + jj;
                    ++c;
                    if (c == KTOP) {
                        mv = topv[q][0]; mp = 0;
                        for (int k = 1; k < KTOP; ++k) {
                            float t = topv[q][k];
                            if (t < mv) { mv = t; mp = k; }
                        }
                    }
                } else if (v > mv) {
                    topv[q][mp] = v;
                    topi[q][mp] = j0 + jj;
                    mv = topv[q][0]; mp = 0;
                    for (int k = 1; k < KTOP; ++k) {
                        float t = topv[q][k];
                        if (t < mv) { mv = t; mp = k; }
                    }
                }
            }
            cnt[q] = c; minv[q] = mv; mpos[q] = mp;
        }
        __syncthreads();
    }

    // epilogue: per query, gather y_ep, gate, write final output
    const int lane = tid & 63, wid = tid >> 6;
    const int dbase = tid * 4;                     // 256 thr * 4 = 1024 = DIM
    for (int q = 0; q < 32; ++q) {
        const int iq = q0 + q;
        const int c = cnt[q];
        float4 ye = {0.f, 0.f, 0.f, 0.f};
        for (int k = 0; k < c; ++k) {
            float v = topv[q][k];          // broadcast
            int   j = topi[q][k];          // broadcast
            float4 h4 = *reinterpret_cast<const float4*>(&hb[(size_t)j * DIM + dbase]);
            ye.x += v * h4.x; ye.y += v * h4.y; ye.z += v * h4.z; ye.w += v * h4.w;
        }
        float* iorow = &io[((size_t)b * SEQT + iq) * DIM];
        float4 ys = *reinterpret_cast<const float4*>(&iorow[dbase]);
        float pd = ye.x * ys.x + ye.y * ys.y + ye.z * ys.z + ye.w * ys.w;
#pragma unroll
        for (int off = 32; off > 0; off >>= 1) pd += __shfl_down(pd, off, 64);
        if (lane == 0) red[wid] = pd;
        __syncthreads();
        if (tid == 0) {
            float z = red[0] + red[1] + red[2] + red[3];
            gateS = 1.f / (1.f + __expf(-z));
        }
        __syncthreads();
        float g = gateS;
        float4 o;
        o.x = g * ye.x + (1.f - g) * ys.x;
        o.y = g * ye.y + (1.f - g) * ys.y;
        o.z = g * ye.z + (1.f - g) * ys.z;
        o.w = g * ye.w + (1.f - g) * ys.w;
        *reinterpret_cast<float4*>(&iorow[dbase]) = o;
        __syncthreads();   // protect red/gateS for next q
    }
}

// ---------------------------------------------------------------------------
extern "C" void kernel_launch(void* const* d_in, const int* in_sizes, int n_in,
                              void* d_out, int out_size, void* d_ws, size_t ws_size,
                              hipStream_t stream) {
    const float* hs = (const float*)d_in[0];   // [NB, SEQT, DIM] fp32
    const float* W  = (const float*)d_in[1];   // [DIM, DIM] fp32
    float* out = (float*)d_out;                // [NB, SEQT, DIM] fp32

    // Stage y_semantic into d_out, then overwrite in place with final result.
    dim3 g1(DIM / 64, (NB * SEQT) / 64);
    ysem_gemm<<<g1, dim3(256), 0, stream>>>(hs, W, out);

    topk_attn<<<dim3(NB * (SEQT / 32)), dim3(256), 0, stream>>>(hs, out);
}

// Round 2
// 3232.998 us; speedup vs baseline: 1.2523x; 1.2523x over previous
//
#include <hip/hip_runtime.h>
#include <math.h>

#define DIM   1024
#define SEQT  2048
#define NB    4
#define SCALE 0.03125f   // 1/32 = DIM^-0.5, exact power of two
#define KTOP  64

// ---------------------------------------------------------------------------
// Kernel 1: y_sem = SCALE * hs @ W   -> written to d_out (staging buffer)
// ---------------------------------------------------------------------------
__global__ __launch_bounds__(256) void ysem_gemm(const float* __restrict__ A,
                                                 const float* __restrict__ W,
                                                 float* __restrict__ C) {
    __shared__ float As[16][68];
    __shared__ float Bs[16][68];

    const int tid = threadIdx.x;
    const int tx = tid & 15, ty = tid >> 4;
    const int n0 = blockIdx.x * 64;
    const int m0 = blockIdx.y * 64;

    const int arow = tid >> 2;
    const int ak   = (tid & 3) * 4;
    const int bk   = tid >> 4;
    const int bn   = (tid & 15) * 4;

    float acc[4][4] = {};

    for (int k0 = 0; k0 < DIM; k0 += 16) {
        float4 av = *reinterpret_cast<const float4*>(&A[(size_t)(m0 + arow) * DIM + k0 + ak]);
        float4 bv = *reinterpret_cast<const float4*>(&W[(size_t)(k0 + bk) * DIM + n0 + bn]);
        As[ak + 0][arow] = av.x;
        As[ak + 1][arow] = av.y;
        As[ak + 2][arow] = av.z;
        As[ak + 3][arow] = av.w;
        *reinterpret_cast<float4*>(&Bs[bk][bn]) = bv;
        __syncthreads();
#pragma unroll
        for (int k = 0; k < 16; ++k) {
            float4 a4 = *reinterpret_cast<const float4*>(&As[k][ty * 4]);
            float4 b4 = *reinterpret_cast<const float4*>(&Bs[k][tx * 4]);
            float ar[4] = {a4.x, a4.y, a4.z, a4.w};
            float br[4] = {b4.x, b4.y, b4.z, b4.w};
#pragma unroll
            for (int i = 0; i < 4; ++i)
#pragma unroll
                for (int j = 0; j < 4; ++j)
                    acc[i][j] += ar[i] * br[j];
        }
        __syncthreads();
    }
#pragma unroll
    for (int i = 0; i < 4; ++i) {
        float4 o;
        o.x = acc[i][0] * SCALE;
        o.y = acc[i][1] * SCALE;
        o.z = acc[i][2] * SCALE;
        o.w = acc[i][3] * SCALE;
        *reinterpret_cast<float4*>(&C[(size_t)(m0 + ty * 4 + i) * DIM + n0 + tx * 4]) = o;
    }
}

// ---------------------------------------------------------------------------
// Kernel A: per (batch, 32-query tile, key-half): fp32 causal scores in
// 64-key tiles -> parallel-filtered running top-64 -> partial lists to ws.
// Grid: NB * 64 * ns blocks (longest qt first), 512 threads.
// ---------------------------------------------------------------------------
__global__ __launch_bounds__(512, 4) void score_partial_topk(
        const float* __restrict__ hs, float* __restrict__ wval,
        int* __restrict__ widx, int* __restrict__ wcnt, int ns) {
    const int bpq = NB * ns;
    const int g   = blockIdx.x;
    const int qt  = 63 - g / bpq;
    const int rem = g % bpq;
    const int b   = rem / ns;
    const int s   = rem % ns;
    const int q0  = qt * 32;
    const int nk  = q0 + 32;          // keys span [0, nk); causality masks the rest

    int lo, hi;
    if (ns == 2) {
        int H = ((nk + 127) >> 7) << 6;   // ~half, rounded to 64
        if (H > nk) H = nk;
        lo = s ? H : 0;
        hi = s ? nk : H;
    } else { lo = 0; hi = nk; }

    const float* hb = hs + (size_t)b * SEQT * DIM;

    __shared__ float   Qs[32][68];
    __shared__ float   Ks[64][68];    // d-slots XOR-swizzled per row-pair
    __shared__ float   sc[32][68];
    __shared__ float   topv[32][65];
    __shared__ int     topi[32][65];
    __shared__ unsigned mask[32][2];
    __shared__ float   minv[32];
    __shared__ int     mvi[32];
    __shared__ int     mpos[32];
    __shared__ int     cnt[32];

    const int tid = threadIdx.x;
    if (tid < 32) { cnt[tid] = 0; minv[tid] = -INFINITY; mvi[tid] = 0; mpos[tid] = 0; }
    __syncthreads();

    const int qp  = tid >> 5;         // 0..15
    const int kp  = tid & 31;         // 0..31
    const int swz = kp & 15;
    const int sr  = tid >> 4;         // Q staging row 0..31
    const int sc4 = (tid & 15) * 4;   // Q staging col

    for (int j0 = lo; j0 < hi; j0 += 64) {
        float a00 = 0.f, a01 = 0.f, a10 = 0.f, a11 = 0.f;

        for (int d0 = 0; d0 < DIM; d0 += 64) {
            // stage Q (scaled) : 512 float4s, one per thread
            float4 qv = *reinterpret_cast<const float4*>(&hb[(size_t)(q0 + sr) * DIM + d0 + sc4]);
            qv.x *= SCALE; qv.y *= SCALE; qv.z *= SCALE; qv.w *= SCALE;
            *reinterpret_cast<float4*>(&Qs[sr][sc4]) = qv;
            // stage K (swizzled slots) : 1024 float4s, two per thread
#pragma unroll
            for (int t = 0; t < 2; ++t) {
                int kid = tid + t * 512;
                int kr  = kid >> 4;
                int kc  = kid & 15;
                float4 kv = *reinterpret_cast<const float4*>(&hb[(size_t)(j0 + kr) * DIM + d0 + kc * 4]);
                int pc = kc ^ ((kr >> 1) & 15);
                *reinterpret_cast<float4*>(&Ks[kr][pc * 4]) = kv;
            }
            __syncthreads();
#pragma unroll
            for (int j = 0; j < 16; ++j) {
                float4 qa = *reinterpret_cast<const float4*>(&Qs[2 * qp][4 * j]);
                float4 qb = *reinterpret_cast<const float4*>(&Qs[2 * qp + 1][4 * j]);
                const int pj = 4 * (j ^ swz);
                float4 ka = *reinterpret_cast<const float4*>(&Ks[2 * kp][pj]);
                float4 kb = *reinterpret_cast<const float4*>(&Ks[2 * kp + 1][pj]);
                a00 += qa.x * ka.x + qa.y * ka.y + qa.z * ka.z + qa.w * ka.w;
                a01 += qa.x * kb.x + qa.y * kb.y + qa.z * kb.z + qa.w * kb.w;
                a10 += qb.x * ka.x + qb.y * ka.y + qb.z * ka.z + qb.w * ka.w;
                a11 += qb.x * kb.x + qb.y * kb.y + qb.z * kb.z + qb.w * kb.w;
            }
            __syncthreads();
        }

        sc[2 * qp][2 * kp]         = a00;
        sc[2 * qp][2 * kp + 1]     = a01;
        sc[2 * qp + 1][2 * kp]     = a10;
        sc[2 * qp + 1][2 * kp + 1] = a11;
        if (tid < 64) mask[tid >> 1][tid & 1] = 0;
        __syncthreads();

        // parallel filter: 16 threads per query mark surviving candidates
        {
            const int q   = tid >> 4;
            const int gsl = tid & 15;
            float4 sv = *reinterpret_cast<const float4*>(&sc[q][4 * gsl]);
            const int iq = q0 + q;
            const float mv = minv[q];
            const int   c  = cnt[q];
            float vv[4] = {sv.x, sv.y, sv.z, sv.w};
            unsigned nib = 0;
#pragma unroll
            for (int e = 0; e < 4; ++e) {
                int jg = j0 + 4 * gsl + e;
                if (jg < iq && (c < KTOP || vv[e] > mv)) nib |= 1u << e;
            }
            if (nib) atomicOr(&mask[q][gsl >> 3], nib << (4 * (gsl & 7)));
        }
        __syncthreads();

        // serial drain: one thread per query processes only set bits
        if (tid < 32) {
            const int q = tid;
            int   c  = cnt[q];
            float mv = minv[q];
            int   mi = mvi[q];
            int   mp = mpos[q];
            auto rescan = [&]() {
                mv = topv[q][0]; mi = topi[q][0]; mp = 0;
                for (int k2 = 1; k2 < KTOP; ++k2) {
                    float t = topv[q][k2]; int ti = topi[q][k2];
                    if (t < mv || (t == mv && ti > mi)) { mv = t; mi = ti; mp = k2; }
                }
            };
#pragma unroll
            for (int w = 0; w < 2; ++w) {
                unsigned m = mask[q][w];
                while (m) {
                    int p = __ffs(m) - 1;
                    m &= m - 1;
                    int jj = 32 * w + p;
                    float v = sc[q][jj];
                    int  ix = j0 + jj;
                    if (c < KTOP) {
                        topv[q][c] = v; topi[q][c] = ix; ++c;
                        if (c == KTOP) rescan();
                    } else if (v > mv) {
                        topv[q][mp] = v; topi[q][mp] = ix;
                        rescan();
                    }
                }
            }
            cnt[q] = c; minv[q] = mv; mvi[q] = mi; mpos[q] = mp;
        }
        __syncthreads();
    }

    // write partial lists (zero-padded) to workspace
    const size_t base = ((size_t)((b * 64 + qt) * ns + s)) << 11;
    for (int e = tid; e < 2048; e += 512) {
        int q = e >> 6, k = e & 63;
        int cq = cnt[q];
        wval[base + e] = (k < cq) ? topv[q][k] : 0.f;
        widx[base + e] = (k < cq) ? topi[q][k] : 0;
    }
    if (tid < 32) wcnt[((b * 64 + qt) * ns + s) * 32 + tid] = cnt[tid];
}

// ---------------------------------------------------------------------------
// Kernel B: merge the ns partial lists (tie-exact), gather y_episodic,
// gate, and write final output over the staged y_sem in io.
// Grid: NB*64 blocks, 1024 threads (1 thread per output dim).
// ---------------------------------------------------------------------------
__global__ __launch_bounds__(1024) void merge_gather(
        const float* __restrict__ hs, const float* __restrict__ wval,
        const int* __restrict__ widx, const int* __restrict__ wcnt,
        float* __restrict__ io, int ns) {
    const int blk = blockIdx.x;
    const int b   = blk >> 6;
    const int qt  = blk & 63;
    const int q0  = qt * 32;
    const float* hb = hs + (size_t)b * SEQT * DIM;

    __shared__ float cv[32][130];
    __shared__ int   ci[32][130];
    __shared__ int   ccnt[2][32];
    __shared__ float topv[32][65];
    __shared__ int   topi[32][65];
    __shared__ float red[16];
    __shared__ float gateS;

    const int tid = threadIdx.x;
    const int tot = ns << 11;
    const size_t ab = ((size_t)((b * 64 + qt) * ns)) << 11;

    for (int f = tid; f < tot; f += 1024) {
        int s = f >> 11, q = (f >> 6) & 31, e = f & 63;
        cv[q][(s << 6) + e] = wval[ab + f];
        ci[q][(s << 6) + e] = widx[ab + f];
    }
    if (tid < ns * 32) {
        int s = tid >> 5, q = tid & 31;
        ccnt[s][q] = wcnt[((b * 64 + qt) * ns + s) * 32 + q];
    }
    __syncthreads();

    if (tid < 32) {
        const int q = tid;
        int c = 0; float mv = -INFINITY; int mi = 0, mp = 0;
        auto rescan = [&]() {
            mv = topv[q][0]; mi = topi[q][0]; mp = 0;
            for (int k2 = 1; k2 < KTOP; ++k2) {
                float t = topv[q][k2]; int ti = topi[q][k2];
                if (t < mv || (t == mv && ti > mi)) { mv = t; mi = ti; mp = k2; }
            }
        };
        for (int s = 0; s < ns; ++s) {
            int n = ccnt[s][q];
            for (int e = 0; e < n; ++e) {
                float v = cv[q][(s << 6) + e];
                int  ix = ci[q][(s << 6) + e];
                if (c < KTOP) {
                    topv[q][c] = v; topi[q][c] = ix; ++c;
                    if (c == KTOP) rescan();
                } else if (v > mv || (v == mv && ix < mi)) {
                    topv[q][mp] = v; topi[q][mp] = ix;
                    rescan();
                }
            }
        }
        for (int k = c; k < KTOP; ++k) { topv[q][k] = 0.f; topi[q][k] = 0; }
    }
    __syncthreads();

    const int d    = tid;           // 1024 threads == DIM
    const int lane = tid & 63;
    const int wid  = tid >> 6;
    for (int q = 0; q < 32; ++q) {
        const int iq = q0 + q;
        float ye = 0.f;
#pragma unroll 4
        for (int k = 0; k < KTOP; ++k) {
            ye += topv[q][k] * hb[(size_t)topi[q][k] * DIM + d];
        }
        float* row = &io[((size_t)b * SEQT + iq) * DIM];
        float ys = row[d];
        float p = ye * ys;
#pragma unroll
        for (int off = 32; off; off >>= 1) p += __shfl_down(p, off, 64);
        if (lane == 0) red[wid] = p;
        __syncthreads();
        if (tid == 0) {
            float z = 0.f;
#pragma unroll
            for (int w = 0; w < 16; ++w) z += red[w];
            gateS = 1.f / (1.f + __expf(-z));
        }
        __syncthreads();
        const float gv = gateS;
        row[d] = gv * ye + (1.f - gv) * ys;
        __syncthreads();
    }
}

// ---------------------------------------------------------------------------
extern "C" void kernel_launch(void* const* d_in, const int* in_sizes, int n_in,
                              void* d_out, int out_size, void* d_ws, size_t ws_size,
                              hipStream_t stream) {
    const float* hs = (const float*)d_in[0];
    const float* W  = (const float*)d_in[1];
    float* out = (float*)d_out;

    // workspace layout: wval[NB*64*ns*2048] f32 | widx[...] i32 | wcnt i32
    int ns = 2;
    {
        size_t entries2 = (size_t)NB * 64 * 2 * 2048;
        size_t need2 = entries2 * 8 + (size_t)NB * 64 * 2 * 32 * 4;
        if (ws_size < need2) ns = 1;
    }
    size_t entries = (size_t)NB * 64 * ns * 2048;
    float* wval = (float*)d_ws;
    int*   widx = (int*)(wval + entries);
    int*   wcnt = widx + entries;

    score_partial_topk<<<dim3(NB * 64 * ns), dim3(512), 0, stream>>>(hs, wval, widx, wcnt, ns);

    dim3 g1(DIM / 64, (NB * SEQT) / 64);
    ysem_gemm<<<g1, dim3(256), 0, stream>>>(hs, W, out);

    merge_gather<<<dim3(NB * 64), dim3(1024), 0, stream>>>(hs, wval, widx, wcnt, out, ns);
}

// Round 4
// 885.213 us; speedup vs baseline: 4.5739x; 3.6522x over previous
//
#include <hip/hip_runtime.h>
#include <math.h>

#define DIM    1024
#define SEQT   2048
#define NB     4
#define SCALE  0.03125f   // 1/32 = DIM^-0.5, exact power of two
#define KTOP   64
#define NTILES 528        // 32*33/2 causal 64x64 tiles per batch
#define DELTA  1e-2f      // fp64-recheck window around the top-k boundary

// ---------------------------------------------------------------------------
// Kernel 1: y_sem = SCALE * hs @ W   -> staged in d_out
// ---------------------------------------------------------------------------
__global__ __launch_bounds__(256) void ysem_gemm(const float* __restrict__ A,
                                                 const float* __restrict__ W,
                                                 float* __restrict__ C) {
    __shared__ float As[16][68];
    __shared__ float Bs[16][68];

    const int tid = threadIdx.x;
    const int tx = tid & 15, ty = tid >> 4;
    const int n0 = blockIdx.x * 64;
    const int m0 = blockIdx.y * 64;

    const int arow = tid >> 2;
    const int ak   = (tid & 3) * 4;
    const int bk   = tid >> 4;
    const int bn   = (tid & 15) * 4;

    float acc[4][4] = {};

    for (int k0 = 0; k0 < DIM; k0 += 16) {
        float4 av = *reinterpret_cast<const float4*>(&A[(size_t)(m0 + arow) * DIM + k0 + ak]);
        float4 bv = *reinterpret_cast<const float4*>(&W[(size_t)(k0 + bk) * DIM + n0 + bn]);
        As[ak + 0][arow] = av.x;
        As[ak + 1][arow] = av.y;
        As[ak + 2][arow] = av.z;
        As[ak + 3][arow] = av.w;
        *reinterpret_cast<float4*>(&Bs[bk][bn]) = bv;
        __syncthreads();
#pragma unroll
        for (int k = 0; k < 16; ++k) {
            float4 a4 = *reinterpret_cast<const float4*>(&As[k][ty * 4]);
            float4 b4 = *reinterpret_cast<const float4*>(&Bs[k][tx * 4]);
            float ar[4] = {a4.x, a4.y, a4.z, a4.w};
            float br[4] = {b4.x, b4.y, b4.z, b4.w};
#pragma unroll
            for (int i = 0; i < 4; ++i)
#pragma unroll
                for (int j = 0; j < 4; ++j)
                    acc[i][j] += ar[i] * br[j];
        }
        __syncthreads();
    }
#pragma unroll
    for (int i = 0; i < 4; ++i) {
        float4 o;
        o.x = acc[i][0] * SCALE;
        o.y = acc[i][1] * SCALE;
        o.z = acc[i][2] * SCALE;
        o.w = acc[i][3] * SCALE;
        *reinterpret_cast<float4*>(&C[(size_t)(m0 + ty * 4 + i) * DIM + n0 + tx * 4]) = o;
    }
}

// ---------------------------------------------------------------------------
// Kernel 2: causal score tiles, exact fp32:  S = SCALE * Q K^T, -inf masked.
// One block per causal 64x64 tile. blockIdx.x = b_loc*NTILES + t.
// ---------------------------------------------------------------------------
__global__ __launch_bounds__(256) void score_gemm(const float* __restrict__ hs,
                                                  float* __restrict__ sc, int b0) {
    const int bl = blockIdx.x / NTILES;
    const int t  = blockIdx.x % NTILES;
    const int b  = b0 + bl;
    int qt = (int)((sqrtf(8.f * t + 1.f) - 1.f) * 0.5f);
    while ((qt + 1) * (qt + 2) / 2 <= t) ++qt;
    while (qt * (qt + 1) / 2 > t) --qt;
    const int kt = t - qt * (qt + 1) / 2;

    const float* Abase = hs + (size_t)b * SEQT * DIM + ((size_t)(qt * 64)) * DIM;
    const float* Bbase = hs + (size_t)b * SEQT * DIM + ((size_t)(kt * 64)) * DIM;

    __shared__ float As[16][68];
    __shared__ float Bs[16][68];

    const int tid = threadIdx.x;
    const int tx = tid & 15, ty = tid >> 4;
    const int arow = tid >> 2;        // 0..63
    const int ak   = (tid & 3) * 4;   // 0,4,8,12

    float acc[4][4] = {};

    for (int k0 = 0; k0 < DIM; k0 += 16) {
        float4 av = *reinterpret_cast<const float4*>(&Abase[(size_t)arow * DIM + k0 + ak]);
        float4 bv = *reinterpret_cast<const float4*>(&Bbase[(size_t)arow * DIM + k0 + ak]);
        As[ak + 0][arow] = av.x;
        As[ak + 1][arow] = av.y;
        As[ak + 2][arow] = av.z;
        As[ak + 3][arow] = av.w;
        Bs[ak + 0][arow] = bv.x;
        Bs[ak + 1][arow] = bv.y;
        Bs[ak + 2][arow] = bv.z;
        Bs[ak + 3][arow] = bv.w;
        __syncthreads();
#pragma unroll
        for (int k = 0; k < 16; ++k) {
            float4 a4 = *reinterpret_cast<const float4*>(&As[k][ty * 4]);
            float4 b4 = *reinterpret_cast<const float4*>(&Bs[k][tx * 4]);
            float ar[4] = {a4.x, a4.y, a4.z, a4.w};
            float br[4] = {b4.x, b4.y, b4.z, b4.w};
#pragma unroll
            for (int i = 0; i < 4; ++i)
#pragma unroll
                for (int j = 0; j < 4; ++j)
                    acc[i][j] += ar[i] * br[j];
        }
        __syncthreads();
    }

    float* tile = sc + ((size_t)bl * NTILES + t) * 4096;
#pragma unroll
    for (int i = 0; i < 4; ++i) {
        const int r  = ty * 4 + i;
        const int gi = qt * 64 + r;
        const int gj = kt * 64 + tx * 4;
        float4 o;
        o.x = (gj + 0 < gi) ? acc[i][0] * SCALE : -INFINITY;
        o.y = (gj + 1 < gi) ? acc[i][1] * SCALE : -INFINITY;
        o.z = (gj + 2 < gi) ? acc[i][2] * SCALE : -INFINITY;
        o.w = (gj + 3 < gi) ? acc[i][3] * SCALE : -INFINITY;
        *reinterpret_cast<float4*>(&tile[r * 64 + tx * 4]) = o;
    }
}

// ---------------------------------------------------------------------------
// Kernel 3: exact top-64 per row via 11-bit radix histogram + tie ranking,
// then fp64 re-check of boundary-window candidates (matches np fp64 top-k).
// One block (256 thr) per row. blockIdx.x = b_loc*SEQT + i.
// ---------------------------------------------------------------------------
__device__ __forceinline__ unsigned flipf(float v) {
    unsigned bu = __float_as_uint(v);
    return bu ^ ((unsigned)((int)bu >> 31) | 0x80000000u);
}

__global__ __launch_bounds__(256) void row_topk(const float* __restrict__ hs,
                                                const float* __restrict__ sc,
                                                float* __restrict__ lv,
                                                int* __restrict__ li, int b0) {
    const int bl = blockIdx.x >> 11;
    const int i  = blockIdx.x & 2047;
    const int b  = b0 + bl;
    const int tid = threadIdx.x;

    float* outv = lv + (((size_t)b * SEQT + i) << 6);
    int*   outi = li + (((size_t)b * SEQT + i) << 6);
    const size_t batch_off = (size_t)bl * NTILES * 4096;

    if (i <= KTOP) {
        // n = i <= 64: select all causal keys, pad with zeros (exact, no flips)
        if (tid < KTOP) {
            float v = 0.f;
            int   ix = 0;
            if (tid < i) {
                const int qt = i >> 6, r = i & 63, kt = tid >> 6;
                const size_t tb = batch_off + ((size_t)(qt * (qt + 1) / 2 + kt)) * 4096;
                v  = sc[tb + r * 64 + (tid & 63)];
                ix = tid;
            }
            outv[tid] = v;
            outi[tid] = ix;
        }
        return;
    }

    const int qt = i >> 6, r = i & 63;
    const int nscan = (qt + 1) * 64;
    const size_t rowb = batch_off + ((size_t)(qt * (qt + 1) / 2)) * 4096 + r * 64;

    float    ev[8];
    unsigned eu[8];
#pragma unroll
    for (int s = 0; s < 8; ++s) {
        const int j = tid + (s << 8);
        ev[s] = (j < nscan) ? sc[rowb + ((size_t)(j >> 6)) * 4096 + (j & 63)] : -INFINITY;
        eu[s] = flipf(ev[s]);
    }

    __shared__ int hist[2048];
    __shared__ int part[256];
    __shared__ int sB, sM;
    for (int h = tid; h < 2048; h += 256) hist[h] = 0;
    __syncthreads();
#pragma unroll
    for (int s = 0; s < 8; ++s) atomicAdd(&hist[eu[s] >> 21], 1);
    __syncthreads();
    {
        int ps = 0;
#pragma unroll
        for (int h = 0; h < 8; ++h) ps += hist[tid * 8 + h];
        part[tid] = ps;
    }
    __syncthreads();
    if (tid == 0) {
        int acc = 0;
        int g = 255;
        for (; g > 0; --g) {
            if (acc + part[g] >= KTOP) break;
            acc += part[g];
        }
        int B = g * 8;
        for (int h = g * 8 + 7; h >= g * 8; --h) {
            if (acc + hist[h] >= KTOP) { B = h; break; }
            acc += hist[h];
        }
        sB = B;
        sM = acc;    // elements in bins > B  (m < 64)
    }
    __syncthreads();
    const unsigned B = (unsigned)sB;
    const int m = sM;
    const int tn = KTOP - m;

    __shared__ unsigned cu[512];
    __shared__ float    cva[512];
    __shared__ int      cix[512];
    __shared__ int      ccnt;
    __shared__ float    lsv[64];      // shared copy of selected values
    if (tid == 0) ccnt = 0;
    __syncthreads();
#pragma unroll
    for (int s = 0; s < 8; ++s) {
        if ((eu[s] >> 21) == B) {
            int p = atomicAdd(&ccnt, 1);
            if (p < 512) { cu[p] = eu[s]; cva[p] = ev[s]; cix[p] = tid + (s << 8); }
        }
    }
    __syncthreads();
    const int cb = (ccnt < 512) ? ccnt : 512;

    // rank boundary-bin candidates by (u desc, idx asc); ranks distinct
    for (int c = tid; c < cb; c += 256) {
        const unsigned u = cu[c];
        const int ix = cix[c];
        int rk = 0;
        for (int c2 = 0; c2 < cb; ++c2) {
            const unsigned u2 = cu[c2];
            rk += (u2 > u) || (u2 == u && cix[c2] < ix);
        }
        if (rk < tn) { outv[m + rk] = cva[c]; outi[m + rk] = ix; lsv[m + rk] = cva[c]; }
    }

    __shared__ int ocnt;
    if (tid == 0) ocnt = 0;
    __syncthreads();
#pragma unroll
    for (int s = 0; s < 8; ++s) {
        if ((eu[s] >> 21) > B) {
            int p = atomicAdd(&ocnt, 1);
            outv[p] = ev[s];
            outi[p] = tid + (s << 8);
            lsv[p]  = ev[s];
        }
    }

    // ---------------- fp64 boundary fixup ----------------
    __shared__ float  svmin;
    __shared__ int    tcnt;
    __shared__ int    spos[64];
    __shared__ double dval[512];
    __syncthreads();                  // lsv complete; cva/cix reusable
    if (tid == 0) {
        float mv = lsv[0];
        for (int k = 1; k < KTOP; ++k) mv = fminf(mv, lsv[k]);
        svmin = mv;
        ccnt = 0;
        tcnt = 0;
    }
    __syncthreads();
    const float vmin = svmin;
    // collect all candidates within the boundary window
#pragma unroll
    for (int s = 0; s < 8; ++s) {
        const int j = tid + (s << 8);
        if (j < nscan && fabsf(ev[s] - vmin) <= DELTA) {
            int p = atomicAdd(&ccnt, 1);
            if (p < 512) { cva[p] = ev[s]; cix[p] = j; }
        }
    }
    __syncthreads();
    const int mb = ccnt;
    if (mb < 2 || mb > 512) return;   // nothing contested (or overflow: keep fp32)

    // borderline slots currently in the list
    if (tid < KTOP && fabsf(lsv[tid] - vmin) <= DELTA) {
        int q = atomicAdd(&tcnt, 1);
        spos[q] = tid;
    }
    __syncthreads();
    const int t = tcnt;

    // exact fp64 rescoring: one wave per candidate
    const int wid = tid >> 6, lane = tid & 63;
    const float* qrow = hs + ((size_t)b * SEQT + i) * DIM;
    for (int c = wid; c < mb; c += 4) {
        const float* krow = hs + ((size_t)b * SEQT + cix[c]) * DIM;
        double acc = 0.0;
        for (int d = lane; d < DIM; d += 64)
            acc += (double)qrow[d] * (double)krow[d];
#pragma unroll
        for (int off = 32; off; off >>= 1) acc += __shfl_xor(acc, off, 64);
        if (lane == 0) dval[c] = acc;    // unscaled (scale > 0, order-preserving)
    }
    __syncthreads();

    // re-select top-t among candidates by (fp64 desc, idx asc); rewrite slots
    if (tid < mb) {
        const double dv = dval[tid];
        const int ix = cix[tid];
        int rk = 0;
        for (int c2 = 0; c2 < mb; ++c2)
            rk += (dval[c2] > dv) || (dval[c2] == dv && cix[c2] < ix);
        if (rk < t) {
            const int pp = spos[rk];
            outv[pp] = cva[tid];         // weight = fp32 score (matches ref ~1e-6)
            outi[pp] = ix;
        }
    }
}

// ---------------------------------------------------------------------------
// Kernel 4: gather y_episodic from top-64 lists, gate, final output.
// One wave per row (lane owns 16 dims). 512 thr = 8 waves, 16 rows/block.
// ---------------------------------------------------------------------------
__global__ __launch_bounds__(512) void merge_gather(const float* __restrict__ hs,
                                                    const float* __restrict__ lv,
                                                    const int* __restrict__ li,
                                                    float* __restrict__ io) {
    const int tid  = threadIdx.x;
    const int lane = tid & 63;
    const int wid  = tid >> 6;
    const int b    = blockIdx.x >> 7;
    const int r0   = (blockIdx.x & 127) * 16;
    const float* hb = hs + (size_t)b * SEQT * DIM;
    const int dbase = lane * 16;

    for (int rr = wid; rr < 16; rr += 8) {
        const int i = r0 + rr;
        const size_t row = (size_t)b * SEQT + i;
        const float4* v4 = reinterpret_cast<const float4*>(lv + (row << 6));
        const int4*   i4 = reinterpret_cast<const int4*>(li + (row << 6));

        float4 y0 = {0.f, 0.f, 0.f, 0.f}, y1 = y0, y2 = y0, y3 = y0;
#pragma unroll 4
        for (int kk = 0; kk < 16; ++kk) {
            const float4 vv = v4[kk];
            const int4   ii = i4[kk];
            {
                const float4* hr = reinterpret_cast<const float4*>(hb + (size_t)ii.x * DIM + dbase);
                float4 a = hr[0], c = hr[1], d = hr[2], e = hr[3];
                y0.x += vv.x * a.x; y0.y += vv.x * a.y; y0.z += vv.x * a.z; y0.w += vv.x * a.w;
                y1.x += vv.x * c.x; y1.y += vv.x * c.y; y1.z += vv.x * c.z; y1.w += vv.x * c.w;
                y2.x += vv.x * d.x; y2.y += vv.x * d.y; y2.z += vv.x * d.z; y2.w += vv.x * d.w;
                y3.x += vv.x * e.x; y3.y += vv.x * e.y; y3.z += vv.x * e.z; y3.w += vv.x * e.w;
            }
            {
                const float4* hr = reinterpret_cast<const float4*>(hb + (size_t)ii.y * DIM + dbase);
                float4 a = hr[0], c = hr[1], d = hr[2], e = hr[3];
                y0.x += vv.y * a.x; y0.y += vv.y * a.y; y0.z += vv.y * a.z; y0.w += vv.y * a.w;
                y1.x += vv.y * c.x; y1.y += vv.y * c.y; y1.z += vv.y * c.z; y1.w += vv.y * c.w;
                y2.x += vv.y * d.x; y2.y += vv.y * d.y; y2.z += vv.y * d.z; y2.w += vv.y * d.w;
                y3.x += vv.y * e.x; y3.y += vv.y * e.y; y3.z += vv.y * e.z; y3.w += vv.y * e.w;
            }
            {
                const float4* hr = reinterpret_cast<const float4*>(hb + (size_t)ii.z * DIM + dbase);
                float4 a = hr[0], c = hr[1], d = hr[2], e = hr[3];
                y0.x += vv.z * a.x; y0.y += vv.z * a.y; y0.z += vv.z * a.z; y0.w += vv.z * a.w;
                y1.x += vv.z * c.x; y1.y += vv.z * c.y; y1.z += vv.z * c.z; y1.w += vv.z * c.w;
                y2.x += vv.z * d.x; y2.y += vv.z * d.y; y2.z += vv.z * d.z; y2.w += vv.z * d.w;
                y3.x += vv.z * e.x; y3.y += vv.z * e.y; y3.z += vv.z * e.z; y3.w += vv.z * e.w;
            }
            {
                const float4* hr = reinterpret_cast<const float4*>(hb + (size_t)ii.w * DIM + dbase);
                float4 a = hr[0], c = hr[1], d = hr[2], e = hr[3];
                y0.x += vv.w * a.x; y0.y += vv.w * a.y; y0.z += vv.w * a.z; y0.w += vv.w * a.w;
                y1.x += vv.w * c.x; y1.y += vv.w * c.y; y1.z += vv.w * c.z; y1.w += vv.w * c.w;
                y2.x += vv.w * d.x; y2.y += vv.w * d.y; y2.z += vv.w * d.z; y2.w += vv.w * d.w;
                y3.x += vv.w * e.x; y3.y += vv.w * e.y; y3.z += vv.w * e.z; y3.w += vv.w * e.w;
            }
        }

        float4* rio = reinterpret_cast<float4*>(io + row * DIM + dbase);
        float4 s0 = rio[0], s1 = rio[1], s2 = rio[2], s3 = rio[3];
        float p = y0.x * s0.x + y0.y * s0.y + y0.z * s0.z + y0.w * s0.w
                + y1.x * s1.x + y1.y * s1.y + y1.z * s1.z + y1.w * s1.w
                + y2.x * s2.x + y2.y * s2.y + y2.z * s2.z + y2.w * s2.w
                + y3.x * s3.x + y3.y * s3.y + y3.z * s3.z + y3.w * s3.w;
#pragma unroll
        for (int off = 32; off; off >>= 1) p += __shfl_xor(p, off, 64);
        const float g  = 1.f / (1.f + __expf(-p));
        const float og = 1.f - g;
        float4 o0, o1, o2, o3;
        o0.x = g * y0.x + og * s0.x; o0.y = g * y0.y + og * s0.y;
        o0.z = g * y0.z + og * s0.z; o0.w = g * y0.w + og * s0.w;
        o1.x = g * y1.x + og * s1.x; o1.y = g * y1.y + og * s1.y;
        o1.z = g * y1.z + og * s1.z; o1.w = g * y1.w + og * s1.w;
        o2.x = g * y2.x + og * s2.x; o2.y = g * y2.y + og * s2.y;
        o2.z = g * y2.z + og * s2.z; o2.w = g * y2.w + og * s2.w;
        o3.x = g * y3.x + og * s3.x; o3.y = g * y3.y + og * s3.y;
        o3.z = g * y3.z + og * s3.z; o3.w = g * y3.w + og * s3.w;
        rio[0] = o0; rio[1] = o1; rio[2] = o2; rio[3] = o3;
    }
}

// ---------------------------------------------------------------------------
extern "C" void kernel_launch(void* const* d_in, const int* in_sizes, int n_in,
                              void* d_out, int out_size, void* d_ws, size_t ws_size,
                              hipStream_t stream) {
    const float* hs = (const float*)d_in[0];
    const float* W  = (const float*)d_in[1];
    float* out = (float*)d_out;

    const size_t lists_f  = (size_t)NB * SEQT * KTOP;               // 524288
    const size_t sc_full  = (size_t)NB * NTILES * 4096;             // floats
    const size_t sc_batch = (size_t)NTILES * 4096;
    const size_t need_full = (sc_full + lists_f) * 4 + lists_f * 4;

    const bool full = (ws_size >= need_full);
    const size_t sc_floats = full ? sc_full : sc_batch;

    float* sc = (float*)d_ws;
    float* lv = sc + sc_floats;
    int*   li = (int*)(lv + lists_f);

    if (full) {
        score_gemm<<<dim3(NB * NTILES), dim3(256), 0, stream>>>(hs, sc, 0);
        row_topk<<<dim3(NB * SEQT), dim3(256), 0, stream>>>(hs, sc, lv, li, 0);
    } else {
        for (int b = 0; b < NB; ++b) {
            score_gemm<<<dim3(NTILES), dim3(256), 0, stream>>>(hs, sc, b);
            row_topk<<<dim3(SEQT), dim3(256), 0, stream>>>(hs, sc, lv, li, b);
        }
    }

    dim3 g1(DIM / 64, (NB * SEQT) / 64);
    ysem_gemm<<<g1, dim3(256), 0, stream>>>(hs, W, out);

    merge_gather<<<dim3(NB * 128), dim3(512), 0, stream>>>(hs, lv, li, out);
}

// Round 5
// 808.365 us; speedup vs baseline: 5.0087x; 1.0951x over previous
//
#include <hip/hip_runtime.h>
#include <math.h>

#define DIM    1024
#define SEQT   2048
#define NB     4
#define SCALE  0.03125f   // 1/32 = DIM^-0.5, exact power of two
#define KTOP   64
#define NT2    136        // 16*17/2 causal 128x128 tiles per batch
#define DELTA  1e-2f      // fp64-recheck window around the top-k boundary

// ---------------------------------------------------------------------------
// Kernel 1: y_sem = SCALE * hs @ W -> staged in d_out.
// 128x128 tile, BK=16, 256 threads, 8x8 split micro-tile (rows/cols at +0,+64).
// ---------------------------------------------------------------------------
__global__ __launch_bounds__(256) void ysem_gemm(const float* __restrict__ A,
                                                 const float* __restrict__ W,
                                                 float* __restrict__ C) {
    __shared__ float As[16][132];   // [k][m]
    __shared__ float Bs[16][132];   // [k][n]

    const int tid = threadIdx.x;
    const int tx = tid & 15, ty = tid >> 4;
    const int n0 = blockIdx.x * 128;
    const int m0 = blockIdx.y * 128;

    const int ar = tid >> 1, ac = (tid & 1) * 8;   // A: row, k-offset (transpose store)
    const int bk = tid >> 4, bn = (tid & 15) * 8;  // B: k, n-offset (direct store)

    float acc[8][8] = {};

    for (int k0 = 0; k0 < DIM; k0 += 16) {
        float4 a0 = *reinterpret_cast<const float4*>(&A[(size_t)(m0 + ar) * DIM + k0 + ac]);
        float4 a1 = *reinterpret_cast<const float4*>(&A[(size_t)(m0 + ar) * DIM + k0 + ac + 4]);
        As[ac + 0][ar] = a0.x; As[ac + 1][ar] = a0.y;
        As[ac + 2][ar] = a0.z; As[ac + 3][ar] = a0.w;
        As[ac + 4][ar] = a1.x; As[ac + 5][ar] = a1.y;
        As[ac + 6][ar] = a1.z; As[ac + 7][ar] = a1.w;
        float4 b0 = *reinterpret_cast<const float4*>(&W[(size_t)(k0 + bk) * DIM + n0 + bn]);
        float4 b1 = *reinterpret_cast<const float4*>(&W[(size_t)(k0 + bk) * DIM + n0 + bn + 4]);
        *reinterpret_cast<float4*>(&Bs[bk][bn])     = b0;
        *reinterpret_cast<float4*>(&Bs[bk][bn + 4]) = b1;
        __syncthreads();
#pragma unroll
        for (int k = 0; k < 16; ++k) {
            float a[8], b[8];
            *reinterpret_cast<float4*>(&a[0]) = *reinterpret_cast<const float4*>(&As[k][ty * 4]);
            *reinterpret_cast<float4*>(&a[4]) = *reinterpret_cast<const float4*>(&As[k][64 + ty * 4]);
            *reinterpret_cast<float4*>(&b[0]) = *reinterpret_cast<const float4*>(&Bs[k][tx * 4]);
            *reinterpret_cast<float4*>(&b[4]) = *reinterpret_cast<const float4*>(&Bs[k][64 + tx * 4]);
#pragma unroll
            for (int i = 0; i < 8; ++i)
#pragma unroll
                for (int j = 0; j < 8; ++j)
                    acc[i][j] += a[i] * b[j];
        }
        __syncthreads();
    }

#pragma unroll
    for (int ih = 0; ih < 2; ++ih)
#pragma unroll
        for (int i = 0; i < 4; ++i) {
            const int r = m0 + ih * 64 + ty * 4 + i;
#pragma unroll
            for (int jh = 0; jh < 2; ++jh) {
                const int c = n0 + jh * 64 + tx * 4;
                const int ii = ih * 4 + i, jj = jh * 4;
                float4 o;
                o.x = acc[ii][jj + 0] * SCALE;
                o.y = acc[ii][jj + 1] * SCALE;
                o.z = acc[ii][jj + 2] * SCALE;
                o.w = acc[ii][jj + 3] * SCALE;
                *reinterpret_cast<float4*>(&C[(size_t)r * DIM + c]) = o;
            }
        }
}

// ---------------------------------------------------------------------------
// Kernel 2: causal 128x128 score tiles, exact fp32: S = SCALE*Q K^T, -inf mask.
// blockIdx.x = b_loc*NT2 + t ; tile t -> (qt, kt), kt <= qt (128-granular).
// ---------------------------------------------------------------------------
__global__ __launch_bounds__(256) void score_gemm(const float* __restrict__ hs,
                                                  float* __restrict__ sc, int b0) {
    const int bl = blockIdx.x / NT2;
    const int t  = blockIdx.x % NT2;
    const int b  = b0 + bl;
    int qt = (int)((sqrtf(8.f * t + 1.f) - 1.f) * 0.5f);
    while ((qt + 1) * (qt + 2) / 2 <= t) ++qt;
    while (qt * (qt + 1) / 2 > t) --qt;
    const int kt = t - qt * (qt + 1) / 2;

    const float* Abase = hs + (size_t)b * SEQT * DIM + ((size_t)(qt * 128)) * DIM;
    const float* Bbase = hs + (size_t)b * SEQT * DIM + ((size_t)(kt * 128)) * DIM;

    __shared__ float As[16][132];
    __shared__ float Bs[16][132];

    const int tid = threadIdx.x;
    const int tx = tid & 15, ty = tid >> 4;
    const int ar = tid >> 1, ac = (tid & 1) * 8;

    float acc[8][8] = {};

    for (int k0 = 0; k0 < DIM; k0 += 16) {
        float4 a0 = *reinterpret_cast<const float4*>(&Abase[(size_t)ar * DIM + k0 + ac]);
        float4 a1 = *reinterpret_cast<const float4*>(&Abase[(size_t)ar * DIM + k0 + ac + 4]);
        As[ac + 0][ar] = a0.x; As[ac + 1][ar] = a0.y;
        As[ac + 2][ar] = a0.z; As[ac + 3][ar] = a0.w;
        As[ac + 4][ar] = a1.x; As[ac + 5][ar] = a1.y;
        As[ac + 6][ar] = a1.z; As[ac + 7][ar] = a1.w;
        float4 b0 = *reinterpret_cast<const float4*>(&Bbase[(size_t)ar * DIM + k0 + ac]);
        float4 b1 = *reinterpret_cast<const float4*>(&Bbase[(size_t)ar * DIM + k0 + ac + 4]);
        Bs[ac + 0][ar] = b0.x; Bs[ac + 1][ar] = b0.y;
        Bs[ac + 2][ar] = b0.z; Bs[ac + 3][ar] = b0.w;
        Bs[ac + 4][ar] = b1.x; Bs[ac + 5][ar] = b1.y;
        Bs[ac + 6][ar] = b1.z; Bs[ac + 7][ar] = b1.w;
        __syncthreads();
#pragma unroll
        for (int k = 0; k < 16; ++k) {
            float a[8], bb[8];
            *reinterpret_cast<float4*>(&a[0])  = *reinterpret_cast<const float4*>(&As[k][ty * 4]);
            *reinterpret_cast<float4*>(&a[4])  = *reinterpret_cast<const float4*>(&As[k][64 + ty * 4]);
            *reinterpret_cast<float4*>(&bb[0]) = *reinterpret_cast<const float4*>(&Bs[k][tx * 4]);
            *reinterpret_cast<float4*>(&bb[4]) = *reinterpret_cast<const float4*>(&Bs[k][64 + tx * 4]);
#pragma unroll
            for (int i = 0; i < 8; ++i)
#pragma unroll
                for (int j = 0; j < 8; ++j)
                    acc[i][j] += a[i] * bb[j];
        }
        __syncthreads();
    }

    float* tile = sc + ((size_t)bl * NT2 + t) * 16384;
#pragma unroll
    for (int ih = 0; ih < 2; ++ih)
#pragma unroll
        for (int i = 0; i < 4; ++i) {
            const int r  = ih * 64 + ty * 4 + i;
            const int gi = qt * 128 + r;
#pragma unroll
            for (int jh = 0; jh < 2; ++jh) {
                const int c  = jh * 64 + tx * 4;
                const int gj = kt * 128 + c;
                const int ii = ih * 4 + i, jj = jh * 4;
                float4 o;
                o.x = (gj + 0 < gi) ? acc[ii][jj + 0] * SCALE : -INFINITY;
                o.y = (gj + 1 < gi) ? acc[ii][jj + 1] * SCALE : -INFINITY;
                o.z = (gj + 2 < gi) ? acc[ii][jj + 2] * SCALE : -INFINITY;
                o.w = (gj + 3 < gi) ? acc[ii][jj + 3] * SCALE : -INFINITY;
                *reinterpret_cast<float4*>(&tile[r * 128 + c]) = o;
            }
        }
}

// ---------------------------------------------------------------------------
// Kernel 3: exact top-64 per row via 11-bit radix histogram + tie ranking,
// then fp64 re-check of boundary-window candidates (matches np fp64 top-k).
// One block (256 thr) per row. blockIdx.x = b_loc*SEQT + i.
// ---------------------------------------------------------------------------
__device__ __forceinline__ unsigned flipf(float v) {
    unsigned bu = __float_as_uint(v);
    return bu ^ ((unsigned)((int)bu >> 31) | 0x80000000u);
}

__global__ __launch_bounds__(256) void row_topk(const float* __restrict__ hs,
                                                const float* __restrict__ sc,
                                                float* __restrict__ lv,
                                                int* __restrict__ li, int b0) {
    const int bl = blockIdx.x >> 11;
    const int i  = blockIdx.x & 2047;
    const int b  = b0 + bl;
    const int tid = threadIdx.x;

    float* outv = lv + (((size_t)b * SEQT + i) << 6);
    int*   outi = li + (((size_t)b * SEQT + i) << 6);
    const size_t batch_off = (size_t)bl * NT2 * 16384;

    if (i <= KTOP) {
        // n = i <= 64: all causal keys (tile qt=0,kt=0), pad with zeros
        if (tid < KTOP) {
            float v = 0.f;
            int   ix = 0;
            if (tid < i) {
                v  = sc[batch_off + (size_t)i * 128 + tid];
                ix = tid;
            }
            outv[tid] = v;
            outi[tid] = ix;
        }
        return;
    }

    const int qt = i >> 7, r = i & 127;
    const int nscan = (qt + 1) * 128;
    const size_t rowb = batch_off + ((size_t)(qt * (qt + 1) / 2)) * 16384 + (size_t)r * 128;

    float    ev[8];
    unsigned eu[8];
#pragma unroll
    for (int s = 0; s < 8; ++s) {
        const int j = tid + (s << 8);
        ev[s] = (j < nscan) ? sc[rowb + ((size_t)(j >> 7)) * 16384 + (j & 127)] : -INFINITY;
        eu[s] = flipf(ev[s]);
    }

    __shared__ int hist[2048];
    __shared__ int part[256];
    __shared__ int sB, sM;
    for (int h = tid; h < 2048; h += 256) hist[h] = 0;
    __syncthreads();
#pragma unroll
    for (int s = 0; s < 8; ++s) atomicAdd(&hist[eu[s] >> 21], 1);
    __syncthreads();
    {
        int ps = 0;
#pragma unroll
        for (int h = 0; h < 8; ++h) ps += hist[tid * 8 + h];
        part[tid] = ps;
    }
    __syncthreads();
    if (tid == 0) {
        int acc = 0;
        int g = 255;
        for (; g > 0; --g) {
            if (acc + part[g] >= KTOP) break;
            acc += part[g];
        }
        int B = g * 8;
        for (int h = g * 8 + 7; h >= g * 8; --h) {
            if (acc + hist[h] >= KTOP) { B = h; break; }
            acc += hist[h];
        }
        sB = B;
        sM = acc;    // elements in bins > B  (m < 64)
    }
    __syncthreads();
    const unsigned B = (unsigned)sB;
    const int m = sM;
    const int tn = KTOP - m;

    __shared__ unsigned cu[512];
    __shared__ float    cva[512];
    __shared__ int      cix[512];
    __shared__ int      ccnt;
    __shared__ float    lsv[64];
    if (tid == 0) ccnt = 0;
    __syncthreads();
#pragma unroll
    for (int s = 0; s < 8; ++s) {
        if ((eu[s] >> 21) == B) {
            int p = atomicAdd(&ccnt, 1);
            if (p < 512) { cu[p] = eu[s]; cva[p] = ev[s]; cix[p] = tid + (s << 8); }
        }
    }
    __syncthreads();
    const int cb = (ccnt < 512) ? ccnt : 512;

    // rank boundary-bin candidates by (u desc, idx asc); ranks distinct
    for (int c = tid; c < cb; c += 256) {
        const unsigned u = cu[c];
        const int ix = cix[c];
        int rk = 0;
        for (int c2 = 0; c2 < cb; ++c2) {
            const unsigned u2 = cu[c2];
            rk += (u2 > u) || (u2 == u && cix[c2] < ix);
        }
        if (rk < tn) { outv[m + rk] = cva[c]; outi[m + rk] = ix; lsv[m + rk] = cva[c]; }
    }

    __shared__ int ocnt;
    if (tid == 0) ocnt = 0;
    __syncthreads();
#pragma unroll
    for (int s = 0; s < 8; ++s) {
        if ((eu[s] >> 21) > B) {
            int p = atomicAdd(&ocnt, 1);
            outv[p] = ev[s];
            outi[p] = tid + (s << 8);
            lsv[p]  = ev[s];
        }
    }

    // ---------------- fp64 boundary fixup ----------------
    __shared__ float  svmin;
    __shared__ int    tcnt;
    __shared__ int    spos[64];
    __shared__ double dval[256];
    __syncthreads();                  // lsv complete; cva/cix reusable
    if (tid == 0) {
        float mv = lsv[0];
        for (int k = 1; k < KTOP; ++k) mv = fminf(mv, lsv[k]);
        svmin = mv;
        ccnt = 0;
        tcnt = 0;
    }
    __syncthreads();
    const float vmin = svmin;
#pragma unroll
    for (int s = 0; s < 8; ++s) {
        const int j = tid + (s << 8);
        if (j < nscan && fabsf(ev[s] - vmin) <= DELTA) {
            int p = atomicAdd(&ccnt, 1);
            if (p < 256) { cva[p] = ev[s]; cix[p] = j; }
        }
    }
    __syncthreads();
    const int mb = ccnt;
    if (mb < 2 || mb > 256) return;   // nothing contested (or overflow: keep fp32)

    if (tid < KTOP && fabsf(lsv[tid] - vmin) <= DELTA) {
        int q = atomicAdd(&tcnt, 1);
        spos[q] = tid;
    }
    __syncthreads();
    const int t = tcnt;

    // exact fp64 rescoring: one wave per candidate
    const int wid = tid >> 6, lane = tid & 63;
    const float* qrow = hs + ((size_t)b * SEQT + i) * DIM;
    for (int c = wid; c < mb; c += 4) {
        const float* krow = hs + ((size_t)b * SEQT + cix[c]) * DIM;
        double acc = 0.0;
        for (int d = lane; d < DIM; d += 64)
            acc += (double)qrow[d] * (double)krow[d];
#pragma unroll
        for (int off = 32; off; off >>= 1) acc += __shfl_xor(acc, off, 64);
        if (lane == 0) dval[c] = acc;
    }
    __syncthreads();

    // re-select top-t among candidates by (fp64 desc, idx asc); rewrite slots
    if (tid < mb) {
        const double dv = dval[tid];
        const int ix = cix[tid];
        int rk = 0;
        for (int c2 = 0; c2 < mb; ++c2)
            rk += (dval[c2] > dv) || (dval[c2] == dv && cix[c2] < ix);
        if (rk < t) {
            const int pp = spos[rk];
            outv[pp] = cva[tid];
            outi[pp] = ix;
        }
    }
}

// ---------------------------------------------------------------------------
// Kernel 4: gather y_episodic from top-64 lists, gate, final output.
// One wave per row; lane owns dims {lane*4 + 256p, p=0..3} -> every memory
// instruction is a contiguous, coalesced 1KB wave access.
// ---------------------------------------------------------------------------
__global__ __launch_bounds__(512) void merge_gather(const float* __restrict__ hs,
                                                    const float* __restrict__ lv,
                                                    const int* __restrict__ li,
                                                    float* __restrict__ io) {
    const int tid  = threadIdx.x;
    const int lane = tid & 63;
    const int wid  = tid >> 6;
    const int b    = blockIdx.x >> 7;
    const int r0   = (blockIdx.x & 127) * 16;
    const float* hb = hs + (size_t)b * SEQT * DIM;
    const int dofs = lane * 4;

    for (int rr = wid; rr < 16; rr += 8) {
        const int i = r0 + rr;
        const size_t row = (size_t)b * SEQT + i;
        const float4* v4 = reinterpret_cast<const float4*>(lv + (row << 6));
        const int4*   i4 = reinterpret_cast<const int4*>(li + (row << 6));

        float4 y0 = {0.f, 0.f, 0.f, 0.f}, y1 = y0, y2 = y0, y3 = y0;
#pragma unroll 4
        for (int kk = 0; kk < 16; ++kk) {
            const float4 vv = v4[kk];
            const int4   ii = i4[kk];
            {
                const float* hr = hb + (size_t)ii.x * DIM + dofs;
                float4 a = *reinterpret_cast<const float4*>(hr);
                float4 c = *reinterpret_cast<const float4*>(hr + 256);
                float4 d = *reinterpret_cast<const float4*>(hr + 512);
                float4 e = *reinterpret_cast<const float4*>(hr + 768);
                y0.x += vv.x * a.x; y0.y += vv.x * a.y; y0.z += vv.x * a.z; y0.w += vv.x * a.w;
                y1.x += vv.x * c.x; y1.y += vv.x * c.y; y1.z += vv.x * c.z; y1.w += vv.x * c.w;
                y2.x += vv.x * d.x; y2.y += vv.x * d.y; y2.z += vv.x * d.z; y2.w += vv.x * d.w;
                y3.x += vv.x * e.x; y3.y += vv.x * e.y; y3.z += vv.x * e.z; y3.w += vv.x * e.w;
            }
            {
                const float* hr = hb + (size_t)ii.y * DIM + dofs;
                float4 a = *reinterpret_cast<const float4*>(hr);
                float4 c = *reinterpret_cast<const float4*>(hr + 256);
                float4 d = *reinterpret_cast<const float4*>(hr + 512);
                float4 e = *reinterpret_cast<const float4*>(hr + 768);
                y0.x += vv.y * a.x; y0.y += vv.y * a.y; y0.z += vv.y * a.z; y0.w += vv.y * a.w;
                y1.x += vv.y * c.x; y1.y += vv.y * c.y; y1.z += vv.y * c.z; y1.w += vv.y * c.w;
                y2.x += vv.y * d.x; y2.y += vv.y * d.y; y2.z += vv.y * d.z; y2.w += vv.y * d.w;
                y3.x += vv.y * e.x; y3.y += vv.y * e.y; y3.z += vv.y * e.z; y3.w += vv.y * e.w;
            }
            {
                const float* hr = hb + (size_t)ii.z * DIM + dofs;
                float4 a = *reinterpret_cast<const float4*>(hr);
                float4 c = *reinterpret_cast<const float4*>(hr + 256);
                float4 d = *reinterpret_cast<const float4*>(hr + 512);
                float4 e = *reinterpret_cast<const float4*>(hr + 768);
                y0.x += vv.z * a.x; y0.y += vv.z * a.y; y0.z += vv.z * a.z; y0.w += vv.z * a.w;
                y1.x += vv.z * c.x; y1.y += vv.z * c.y; y1.z += vv.z * c.z; y1.w += vv.z * c.w;
                y2.x += vv.z * d.x; y2.y += vv.z * d.y; y2.z += vv.z * d.z; y2.w += vv.z * d.w;
                y3.x += vv.z * e.x; y3.y += vv.z * e.y; y3.z += vv.z * e.z; y3.w += vv.z * e.w;
            }
            {
                const float* hr = hb + (size_t)ii.w * DIM + dofs;
                float4 a = *reinterpret_cast<const float4*>(hr);
                float4 c = *reinterpret_cast<const float4*>(hr + 256);
                float4 d = *reinterpret_cast<const float4*>(hr + 512);
                float4 e = *reinterpret_cast<const float4*>(hr + 768);
                y0.x += vv.w * a.x; y0.y += vv.w * a.y; y0.z += vv.w * a.z; y0.w += vv.w * a.w;
                y1.x += vv.w * c.x; y1.y += vv.w * c.y; y1.z += vv.w * c.z; y1.w += vv.w * c.w;
                y2.x += vv.w * d.x; y2.y += vv.w * d.y; y2.z += vv.w * d.z; y2.w += vv.w * d.w;
                y3.x += vv.w * e.x; y3.y += vv.w * e.y; y3.z += vv.w * e.z; y3.w += vv.w * e.w;
            }
        }

        float* iorow = io + row * DIM + dofs;
        float4 s0 = *reinterpret_cast<const float4*>(iorow);
        float4 s1 = *reinterpret_cast<const float4*>(iorow + 256);
        float4 s2 = *reinterpret_cast<const float4*>(iorow + 512);
        float4 s3 = *reinterpret_cast<const float4*>(iorow + 768);
        float p = y0.x * s0.x + y0.y * s0.y + y0.z * s0.z + y0.w * s0.w
                + y1.x * s1.x + y1.y * s1.y + y1.z * s1.z + y1.w * s1.w
                + y2.x * s2.x + y2.y * s2.y + y2.z * s2.z + y2.w * s2.w
                + y3.x * s3.x + y3.y * s3.y + y3.z * s3.z + y3.w * s3.w;
#pragma unroll
        for (int off = 32; off; off >>= 1) p += __shfl_xor(p, off, 64);
        const float g  = 1.f / (1.f + __expf(-p));
        const float og = 1.f - g;
        float4 o0, o1, o2, o3;
        o0.x = g * y0.x + og * s0.x; o0.y = g * y0.y + og * s0.y;
        o0.z = g * y0.z + og * s0.z; o0.w = g * y0.w + og * s0.w;
        o1.x = g * y1.x + og * s1.x; o1.y = g * y1.y + og * s1.y;
        o1.z = g * y1.z + og * s1.z; o1.w = g * y1.w + og * s1.w;
        o2.x = g * y2.x + og * s2.x; o2.y = g * y2.y + og * s2.y;
        o2.z = g * y2.z + og * s2.z; o2.w = g * y2.w + og * s2.w;
        o3.x = g * y3.x + og * s3.x; o3.y = g * y3.y + og * s3.y;
        o3.z = g * y3.z + og * s3.z; o3.w = g * y3.w + og * s3.w;
        *reinterpret_cast<float4*>(iorow)       = o0;
        *reinterpret_cast<float4*>(iorow + 256) = o1;
        *reinterpret_cast<float4*>(iorow + 512) = o2;
        *reinterpret_cast<float4*>(iorow + 768) = o3;
    }
}

// ---------------------------------------------------------------------------
extern "C" void kernel_launch(void* const* d_in, const int* in_sizes, int n_in,
                              void* d_out, int out_size, void* d_ws, size_t ws_size,
                              hipStream_t stream) {
    const float* hs = (const float*)d_in[0];
    const float* W  = (const float*)d_in[1];
    float* out = (float*)d_out;

    const size_t lists_f  = (size_t)NB * SEQT * KTOP;            // 524288
    const size_t sc_full  = (size_t)NB * NT2 * 16384;            // floats
    const size_t sc_batch = (size_t)NT2 * 16384;
    const size_t need_full = (sc_full + lists_f) * 4 + lists_f * 4;

    const bool full = (ws_size >= need_full);
    const size_t sc_floats = full ? sc_full : sc_batch;

    float* sc = (float*)d_ws;
    float* lv = sc + sc_floats;
    int*   li = (int*)(lv + lists_f);

    if (full) {
        score_gemm<<<dim3(NB * NT2), dim3(256), 0, stream>>>(hs, sc, 0);
        row_topk<<<dim3(NB * SEQT), dim3(256), 0, stream>>>(hs, sc, lv, li, 0);
    } else {
        for (int b = 0; b < NB; ++b) {
            score_gemm<<<dim3(NT2), dim3(256), 0, stream>>>(hs, sc, b);
            row_topk<<<dim3(SEQT), dim3(256), 0, stream>>>(hs, sc, lv, li, b);
        }
    }

    dim3 g1(DIM / 128, (NB * SEQT) / 128);
    ysem_gemm<<<g1, dim3(256), 0, stream>>>(hs, W, out);

    merge_gather<<<dim3(NB * 128), dim3(512), 0, stream>>>(hs, lv, li, out);
}

// Round 6
// 467.854 us; speedup vs baseline: 8.6540x; 1.7278x over previous
//
#include <hip/hip_runtime.h>
#include <hip/hip_bf16.h>
#include <math.h>

#define DIM    1024
#define SEQT   2048
#define NB     4
#define SCALE  0.03125f   // 1/32 = DIM^-0.5, exact power of two
#define KTOP   64
#define NT2    136        // 16*17/2 causal 128x128 tiles per batch
#define DELTA  1e-2f      // fp64-recheck window around the top-k boundary

typedef __attribute__((ext_vector_type(8))) short short8;   // 8 bf16 = 4 VGPR
typedef __attribute__((ext_vector_type(4))) float f32x4;    // MFMA C/D frag

// ---- bf16 RNE helpers (manual, deterministic) ------------------------------
__device__ __forceinline__ unsigned short bfr(float x) {
    unsigned u = __float_as_uint(x);
    unsigned r = (u + 0x7fffu + ((u >> 16) & 1u)) >> 16;
    return (unsigned short)r;
}
__device__ __forceinline__ float bf2f(unsigned short h) {
    return __uint_as_float(((unsigned)h) << 16);
}

// ---------------------------------------------------------------------------
// split_bf16: x -> hi = bf16(x), lo = bf16(x - hi)   (grid-stride, float4)
// ---------------------------------------------------------------------------
__global__ __launch_bounds__(256) void split_bf16(const float* __restrict__ x,
                                                  unsigned short* __restrict__ hi,
                                                  unsigned short* __restrict__ lo,
                                                  int n4) {
    const int stride = gridDim.x * 256;
    for (int idx = blockIdx.x * 256 + threadIdx.x; idx < n4; idx += stride) {
        float4 v = reinterpret_cast<const float4*>(x)[idx];
        ushort4 h, l;
        h.x = bfr(v.x); l.x = bfr(v.x - bf2f(h.x));
        h.y = bfr(v.y); l.y = bfr(v.y - bf2f(h.y));
        h.z = bfr(v.z); l.z = bfr(v.z - bf2f(h.z));
        h.w = bfr(v.w); l.w = bfr(v.w - bf2f(h.w));
        reinterpret_cast<ushort4*>(hi)[idx] = h;
        reinterpret_cast<ushort4*>(lo)[idx] = l;
    }
}

// ---------------------------------------------------------------------------
// wtrans_split: Wt[n][k] = W[k][n] as hi/lo bf16 (64x64 LDS tile transpose)
// ---------------------------------------------------------------------------
__global__ __launch_bounds__(256) void wtrans_split(const float* __restrict__ W,
                                                    unsigned short* __restrict__ thi,
                                                    unsigned short* __restrict__ tlo) {
    __shared__ float tle[64][65];
    const int n0 = blockIdx.x * 64, k0 = blockIdx.y * 64;
    const int tid = threadIdx.x;
    const int r = tid >> 2, c0 = (tid & 3) * 16;
#pragma unroll
    for (int s = 0; s < 16; s += 4) {
        float4 v = *reinterpret_cast<const float4*>(&W[(size_t)(k0 + r) * DIM + n0 + c0 + s]);
        tle[r][c0 + s + 0] = v.x; tle[r][c0 + s + 1] = v.y;
        tle[r][c0 + s + 2] = v.z; tle[r][c0 + s + 3] = v.w;
    }
    __syncthreads();
#pragma unroll
    for (int s = 0; s < 16; s += 4) {
        float a0 = tle[c0 + s + 0][r];
        float a1 = tle[c0 + s + 1][r];
        float a2 = tle[c0 + s + 2][r];
        float a3 = tle[c0 + s + 3][r];
        ushort4 h, l;
        h.x = bfr(a0); l.x = bfr(a0 - bf2f(h.x));
        h.y = bfr(a1); l.y = bfr(a1 - bf2f(h.y));
        h.z = bfr(a2); l.z = bfr(a2 - bf2f(h.z));
        h.w = bfr(a3); l.w = bfr(a3 - bf2f(h.w));
        *reinterpret_cast<ushort4*>(&thi[(size_t)(n0 + r) * DIM + k0 + c0 + s]) = h;
        *reinterpret_cast<ushort4*>(&tlo[(size_t)(n0 + r) * DIM + k0 + c0 + s]) = l;
    }
}

// ---------------------------------------------------------------------------
// score_mfma: causal 128x128 score tiles via bf16 split-3 MFMA, -inf masked.
// 256 thr = 4 waves (2x2); wave owns 64x64 = 4x4 frags of 16x16x32.
// ---------------------------------------------------------------------------
__global__ __launch_bounds__(256) void score_mfma(const unsigned short* __restrict__ hhi,
                                                  const unsigned short* __restrict__ hlo,
                                                  float* __restrict__ sc, int b0) {
    const int bl = blockIdx.x / NT2;
    const int t  = blockIdx.x % NT2;
    const int b  = b0 + bl;
    int qt = (int)((sqrtf(8.f * t + 1.f) - 1.f) * 0.5f);
    while ((qt + 1) * (qt + 2) / 2 <= t) ++qt;
    while (qt * (qt + 1) / 2 > t) --qt;
    const int kt = t - qt * (qt + 1) / 2;

    const size_t base = (size_t)b * SEQT * DIM;
    const unsigned short* Ah = hhi + base + (size_t)(qt * 128) * DIM;
    const unsigned short* Al = hlo + base + (size_t)(qt * 128) * DIM;
    const unsigned short* Bh = hhi + base + (size_t)(kt * 128) * DIM;
    const unsigned short* Bl = hlo + base + (size_t)(kt * 128) * DIM;

    __shared__ unsigned short lds[4][128][40];   // Ahi, Alo, Bhi, Blo ; 40KB

    const int tid  = threadIdx.x;
    const int lane = tid & 63, wid = tid >> 6;
    const int wr = (wid >> 1) * 64, wc = (wid & 1) * 64;
    const int fr = lane & 15, fc = lane >> 4;

    const int sr  = tid >> 2;          // staging row 0..63 (and +64)
    const int scg = (tid & 3) * 8;     // k-granule offset (8 bf16 = 16B)

    f32x4 acc[4][4];
    const f32x4 zz = {0.f, 0.f, 0.f, 0.f};
#pragma unroll
    for (int i = 0; i < 4; ++i)
#pragma unroll
        for (int j = 0; j < 4; ++j) acc[i][j] = zz;

    for (int k0 = 0; k0 < DIM; k0 += 32) {
        int4 va0 = *reinterpret_cast<const int4*>(Ah + (size_t)sr * DIM + k0 + scg);
        int4 va1 = *reinterpret_cast<const int4*>(Ah + (size_t)(sr + 64) * DIM + k0 + scg);
        int4 va2 = *reinterpret_cast<const int4*>(Al + (size_t)sr * DIM + k0 + scg);
        int4 va3 = *reinterpret_cast<const int4*>(Al + (size_t)(sr + 64) * DIM + k0 + scg);
        int4 vb0 = *reinterpret_cast<const int4*>(Bh + (size_t)sr * DIM + k0 + scg);
        int4 vb1 = *reinterpret_cast<const int4*>(Bh + (size_t)(sr + 64) * DIM + k0 + scg);
        int4 vb2 = *reinterpret_cast<const int4*>(Bl + (size_t)sr * DIM + k0 + scg);
        int4 vb3 = *reinterpret_cast<const int4*>(Bl + (size_t)(sr + 64) * DIM + k0 + scg);
        __syncthreads();
        *reinterpret_cast<int4*>(&lds[0][sr][scg])      = va0;
        *reinterpret_cast<int4*>(&lds[0][sr + 64][scg]) = va1;
        *reinterpret_cast<int4*>(&lds[1][sr][scg])      = va2;
        *reinterpret_cast<int4*>(&lds[1][sr + 64][scg]) = va3;
        *reinterpret_cast<int4*>(&lds[2][sr][scg])      = vb0;
        *reinterpret_cast<int4*>(&lds[2][sr + 64][scg]) = vb1;
        *reinterpret_cast<int4*>(&lds[3][sr][scg])      = vb2;
        *reinterpret_cast<int4*>(&lds[3][sr + 64][scg]) = vb3;
        __syncthreads();

        short8 ah[4], al4[4], bh4[4], bl4[4];
#pragma unroll
        for (int f = 0; f < 4; ++f) {
            ah[f]  = *reinterpret_cast<const short8*>(&lds[0][wr + f * 16 + fr][fc * 8]);
            al4[f] = *reinterpret_cast<const short8*>(&lds[1][wr + f * 16 + fr][fc * 8]);
            bh4[f] = *reinterpret_cast<const short8*>(&lds[2][wc + f * 16 + fr][fc * 8]);
            bl4[f] = *reinterpret_cast<const short8*>(&lds[3][wc + f * 16 + fr][fc * 8]);
        }
#pragma unroll
        for (int i = 0; i < 4; ++i)
#pragma unroll
            for (int j = 0; j < 4; ++j) {
                acc[i][j] = __builtin_amdgcn_mfma_f32_16x16x32_bf16(ah[i],  bh4[j], acc[i][j], 0, 0, 0);
                acc[i][j] = __builtin_amdgcn_mfma_f32_16x16x32_bf16(ah[i],  bl4[j], acc[i][j], 0, 0, 0);
                acc[i][j] = __builtin_amdgcn_mfma_f32_16x16x32_bf16(al4[i], bh4[j], acc[i][j], 0, 0, 0);
            }
    }

    float* tile = sc + ((size_t)bl * NT2 + t) * 16384;
    const bool diag = (qt == kt);
#pragma unroll
    for (int i = 0; i < 4; ++i)
#pragma unroll
        for (int j = 0; j < 4; ++j)
#pragma unroll
            for (int v = 0; v < 4; ++v) {
                const int row = wr + i * 16 + fc * 4 + v;
                const int col = wc + j * 16 + fr;
                float val = acc[i][j][v] * SCALE;
                if (diag && col >= row) val = -INFINITY;
                tile[row * 128 + col] = val;
            }
}

// ---------------------------------------------------------------------------
// ysem_mfma: C = SCALE * A @ W via bf16 split-3 MFMA; B given transposed.
// grid.x = N/128, grid.y = M/128.
// ---------------------------------------------------------------------------
__global__ __launch_bounds__(256) void ysem_mfma(const unsigned short* __restrict__ ahi,
                                                 const unsigned short* __restrict__ alo,
                                                 const unsigned short* __restrict__ wthi,
                                                 const unsigned short* __restrict__ wtlo,
                                                 float* __restrict__ C) {
    const int n0 = blockIdx.x * 128;
    const int m0 = blockIdx.y * 128;
    const unsigned short* Ah = ahi + (size_t)m0 * DIM;
    const unsigned short* Al = alo + (size_t)m0 * DIM;
    const unsigned short* Bh = wthi + (size_t)n0 * DIM;
    const unsigned short* Bl = wtlo + (size_t)n0 * DIM;

    __shared__ unsigned short lds[4][128][40];

    const int tid  = threadIdx.x;
    const int lane = tid & 63, wid = tid >> 6;
    const int wr = (wid >> 1) * 64, wc = (wid & 1) * 64;
    const int fr = lane & 15, fc = lane >> 4;
    const int sr  = tid >> 2;
    const int scg = (tid & 3) * 8;

    f32x4 acc[4][4];
    const f32x4 zz = {0.f, 0.f, 0.f, 0.f};
#pragma unroll
    for (int i = 0; i < 4; ++i)
#pragma unroll
        for (int j = 0; j < 4; ++j) acc[i][j] = zz;

    for (int k0 = 0; k0 < DIM; k0 += 32) {
        int4 va0 = *reinterpret_cast<const int4*>(Ah + (size_t)sr * DIM + k0 + scg);
        int4 va1 = *reinterpret_cast<const int4*>(Ah + (size_t)(sr + 64) * DIM + k0 + scg);
        int4 va2 = *reinterpret_cast<const int4*>(Al + (size_t)sr * DIM + k0 + scg);
        int4 va3 = *reinterpret_cast<const int4*>(Al + (size_t)(sr + 64) * DIM + k0 + scg);
        int4 vb0 = *reinterpret_cast<const int4*>(Bh + (size_t)sr * DIM + k0 + scg);
        int4 vb1 = *reinterpret_cast<const int4*>(Bh + (size_t)(sr + 64) * DIM + k0 + scg);
        int4 vb2 = *reinterpret_cast<const int4*>(Bl + (size_t)sr * DIM + k0 + scg);
        int4 vb3 = *reinterpret_cast<const int4*>(Bl + (size_t)(sr + 64) * DIM + k0 + scg);
        __syncthreads();
        *reinterpret_cast<int4*>(&lds[0][sr][scg])      = va0;
        *reinterpret_cast<int4*>(&lds[0][sr + 64][scg]) = va1;
        *reinterpret_cast<int4*>(&lds[1][sr][scg])      = va2;
        *reinterpret_cast<int4*>(&lds[1][sr + 64][scg]) = va3;
        *reinterpret_cast<int4*>(&lds[2][sr][scg])      = vb0;
        *reinterpret_cast<int4*>(&lds[2][sr + 64][scg]) = vb1;
        *reinterpret_cast<int4*>(&lds[3][sr][scg])      = vb2;
        *reinterpret_cast<int4*>(&lds[3][sr + 64][scg]) = vb3;
        __syncthreads();

        short8 ah[4], al4[4], bh4[4], bl4[4];
#pragma unroll
        for (int f = 0; f < 4; ++f) {
            ah[f]  = *reinterpret_cast<const short8*>(&lds[0][wr + f * 16 + fr][fc * 8]);
            al4[f] = *reinterpret_cast<const short8*>(&lds[1][wr + f * 16 + fr][fc * 8]);
            bh4[f] = *reinterpret_cast<const short8*>(&lds[2][wc + f * 16 + fr][fc * 8]);
            bl4[f] = *reinterpret_cast<const short8*>(&lds[3][wc + f * 16 + fr][fc * 8]);
        }
#pragma unroll
        for (int i = 0; i < 4; ++i)
#pragma unroll
            for (int j = 0; j < 4; ++j) {
                acc[i][j] = __builtin_amdgcn_mfma_f32_16x16x32_bf16(ah[i],  bh4[j], acc[i][j], 0, 0, 0);
                acc[i][j] = __builtin_amdgcn_mfma_f32_16x16x32_bf16(ah[i],  bl4[j], acc[i][j], 0, 0, 0);
                acc[i][j] = __builtin_amdgcn_mfma_f32_16x16x32_bf16(al4[i], bh4[j], acc[i][j], 0, 0, 0);
            }
    }

#pragma unroll
    for (int i = 0; i < 4; ++i)
#pragma unroll
        for (int j = 0; j < 4; ++j)
#pragma unroll
            for (int v = 0; v < 4; ++v) {
                const int row = wr + i * 16 + fc * 4 + v;
                const int col = wc + j * 16 + fr;
                C[(size_t)(m0 + row) * DIM + n0 + col] = acc[i][j][v] * SCALE;
            }
}

// ---------------------------------------------------------------------------
// Kernel 3: exact top-64 per row via 11-bit radix histogram + tie ranking,
// then fp64 re-check of boundary-window candidates (matches np fp64 top-k).
// ---------------------------------------------------------------------------
__device__ __forceinline__ unsigned flipf(float v) {
    unsigned bu = __float_as_uint(v);
    return bu ^ ((unsigned)((int)bu >> 31) | 0x80000000u);
}

__global__ __launch_bounds__(256) void row_topk(const float* __restrict__ hs,
                                                const float* __restrict__ sc,
                                                float* __restrict__ lv,
                                                int* __restrict__ li, int b0) {
    const int bl = blockIdx.x >> 11;
    const int i  = blockIdx.x & 2047;
    const int b  = b0 + bl;
    const int tid = threadIdx.x;

    float* outv = lv + (((size_t)b * SEQT + i) << 6);
    int*   outi = li + (((size_t)b * SEQT + i) << 6);
    const size_t batch_off = (size_t)bl * NT2 * 16384;

    if (i <= KTOP) {
        if (tid < KTOP) {
            float v = 0.f;
            int   ix = 0;
            if (tid < i) {
                v  = sc[batch_off + (size_t)i * 128 + tid];
                ix = tid;
            }
            outv[tid] = v;
            outi[tid] = ix;
        }
        return;
    }

    const int qt = i >> 7, r = i & 127;
    const int nscan = (qt + 1) * 128;
    const size_t rowb = batch_off + ((size_t)(qt * (qt + 1) / 2)) * 16384 + (size_t)r * 128;

    float    ev[8];
    unsigned eu[8];
#pragma unroll
    for (int s = 0; s < 8; ++s) {
        const int j = tid + (s << 8);
        ev[s] = (j < nscan) ? sc[rowb + ((size_t)(j >> 7)) * 16384 + (j & 127)] : -INFINITY;
        eu[s] = flipf(ev[s]);
    }

    __shared__ int hist[2048];
    __shared__ int part[256];
    __shared__ int sB, sM;
    for (int h = tid; h < 2048; h += 256) hist[h] = 0;
    __syncthreads();
#pragma unroll
    for (int s = 0; s < 8; ++s) atomicAdd(&hist[eu[s] >> 21], 1);
    __syncthreads();
    {
        int ps = 0;
#pragma unroll
        for (int h = 0; h < 8; ++h) ps += hist[tid * 8 + h];
        part[tid] = ps;
    }
    __syncthreads();
    if (tid == 0) {
        int acc = 0;
        int g = 255;
        for (; g > 0; --g) {
            if (acc + part[g] >= KTOP) break;
            acc += part[g];
        }
        int B = g * 8;
        for (int h = g * 8 + 7; h >= g * 8; --h) {
            if (acc + hist[h] >= KTOP) { B = h; break; }
            acc += hist[h];
        }
        sB = B;
        sM = acc;
    }
    __syncthreads();
    const unsigned B = (unsigned)sB;
    const int m = sM;
    const int tn = KTOP - m;

    __shared__ unsigned cu[512];
    __shared__ float    cva[512];
    __shared__ int      cix[512];
    __shared__ int      ccnt;
    __shared__ float    lsv[64];
    if (tid == 0) ccnt = 0;
    __syncthreads();
#pragma unroll
    for (int s = 0; s < 8; ++s) {
        if ((eu[s] >> 21) == B) {
            int p = atomicAdd(&ccnt, 1);
            if (p < 512) { cu[p] = eu[s]; cva[p] = ev[s]; cix[p] = tid + (s << 8); }
        }
    }
    __syncthreads();
    const int cb = (ccnt < 512) ? ccnt : 512;

    for (int c = tid; c < cb; c += 256) {
        const unsigned u = cu[c];
        const int ix = cix[c];
        int rk = 0;
        for (int c2 = 0; c2 < cb; ++c2) {
            const unsigned u2 = cu[c2];
            rk += (u2 > u) || (u2 == u && cix[c2] < ix);
        }
        if (rk < tn) { outv[m + rk] = cva[c]; outi[m + rk] = ix; lsv[m + rk] = cva[c]; }
    }

    __shared__ int ocnt;
    if (tid == 0) ocnt = 0;
    __syncthreads();
#pragma unroll
    for (int s = 0; s < 8; ++s) {
        if ((eu[s] >> 21) > B) {
            int p = atomicAdd(&ocnt, 1);
            outv[p] = ev[s];
            outi[p] = tid + (s << 8);
            lsv[p]  = ev[s];
        }
    }

    // ---------------- fp64 boundary fixup ----------------
    __shared__ float  svmin;
    __shared__ int    tcnt;
    __shared__ int    spos[64];
    __shared__ double dval[256];
    __syncthreads();
    if (tid == 0) {
        float mv = lsv[0];
        for (int k = 1; k < KTOP; ++k) mv = fminf(mv, lsv[k]);
        svmin = mv;
        ccnt = 0;
        tcnt = 0;
    }
    __syncthreads();
    const float vmin = svmin;
#pragma unroll
    for (int s = 0; s < 8; ++s) {
        const int j = tid + (s << 8);
        if (j < nscan && fabsf(ev[s] - vmin) <= DELTA) {
            int p = atomicAdd(&ccnt, 1);
            if (p < 256) { cva[p] = ev[s]; cix[p] = j; }
        }
    }
    __syncthreads();
    const int mb = ccnt;
    if (mb < 2 || mb > 256) return;

    if (tid < KTOP && fabsf(lsv[tid] - vmin) <= DELTA) {
        int q = atomicAdd(&tcnt, 1);
        spos[q] = tid;
    }
    __syncthreads();
    const int t = tcnt;

    const int wid = tid >> 6, lane = tid & 63;
    const float* qrow = hs + ((size_t)b * SEQT + i) * DIM;
    for (int c = wid; c < mb; c += 4) {
        const float* krow = hs + ((size_t)b * SEQT + cix[c]) * DIM;
        double acc = 0.0;
        for (int d = lane; d < DIM; d += 64)
            acc += (double)qrow[d] * (double)krow[d];
#pragma unroll
        for (int off = 32; off; off >>= 1) acc += __shfl_xor(acc, off, 64);
        if (lane == 0) dval[c] = acc;
    }
    __syncthreads();

    if (tid < mb) {
        const double dv = dval[tid];
        const int ix = cix[tid];
        int rk = 0;
        for (int c2 = 0; c2 < mb; ++c2)
            rk += (dval[c2] > dv) || (dval[c2] == dv && cix[c2] < ix);
        if (rk < t) {
            const int pp = spos[rk];
            outv[pp] = cva[tid];
            outi[pp] = ix;
        }
    }
}

// ---------------------------------------------------------------------------
// Kernel 4: gather y_episodic from top-64 lists, gate, final output.
// One wave per row; lane owns dims {lane*4 + 256p} -> fully coalesced.
// ---------------------------------------------------------------------------
__global__ __launch_bounds__(512) void merge_gather(const float* __restrict__ hs,
                                                    const float* __restrict__ lv,
                                                    const int* __restrict__ li,
                                                    float* __restrict__ io) {
    const int tid  = threadIdx.x;
    const int lane = tid & 63;
    const int wid  = tid >> 6;
    const int b    = blockIdx.x >> 7;
    const int r0   = (blockIdx.x & 127) * 16;
    const float* hb = hs + (size_t)b * SEQT * DIM;
    const int dofs = lane * 4;

    for (int rr = wid; rr < 16; rr += 8) {
        const int i = r0 + rr;
        const size_t row = (size_t)b * SEQT + i;
        const float4* v4 = reinterpret_cast<const float4*>(lv + (row << 6));
        const int4*   i4 = reinterpret_cast<const int4*>(li + (row << 6));

        float4 y0 = {0.f, 0.f, 0.f, 0.f}, y1 = y0, y2 = y0, y3 = y0;
#pragma unroll 4
        for (int kk = 0; kk < 16; ++kk) {
            const float4 vv = v4[kk];
            const int4   ii = i4[kk];
            {
                const float* hr = hb + (size_t)ii.x * DIM + dofs;
                float4 a = *reinterpret_cast<const float4*>(hr);
                float4 c = *reinterpret_cast<const float4*>(hr + 256);
                float4 d = *reinterpret_cast<const float4*>(hr + 512);
                float4 e = *reinterpret_cast<const float4*>(hr + 768);
                y0.x += vv.x * a.x; y0.y += vv.x * a.y; y0.z += vv.x * a.z; y0.w += vv.x * a.w;
                y1.x += vv.x * c.x; y1.y += vv.x * c.y; y1.z += vv.x * c.z; y1.w += vv.x * c.w;
                y2.x += vv.x * d.x; y2.y += vv.x * d.y; y2.z += vv.x * d.z; y2.w += vv.x * d.w;
                y3.x += vv.x * e.x; y3.y += vv.x * e.y; y3.z += vv.x * e.z; y3.w += vv.x * e.w;
            }
            {
                const float* hr = hb + (size_t)ii.y * DIM + dofs;
                float4 a = *reinterpret_cast<const float4*>(hr);
                float4 c = *reinterpret_cast<const float4*>(hr + 256);
                float4 d = *reinterpret_cast<const float4*>(hr + 512);
                float4 e = *reinterpret_cast<const float4*>(hr + 768);
                y0.x += vv.y * a.x; y0.y += vv.y * a.y; y0.z += vv.y * a.z; y0.w += vv.y * a.w;
                y1.x += vv.y * c.x; y1.y += vv.y * c.y; y1.z += vv.y * c.z; y1.w += vv.y * c.w;
                y2.x += vv.y * d.x; y2.y += vv.y * d.y; y2.z += vv.y * d.z; y2.w += vv.y * d.w;
                y3.x += vv.y * e.x; y3.y += vv.y * e.y; y3.z += vv.y * e.z; y3.w += vv.y * e.w;
            }
            {
                const float* hr = hb + (size_t)ii.z * DIM + dofs;
                float4 a = *reinterpret_cast<const float4*>(hr);
                float4 c = *reinterpret_cast<const float4*>(hr + 256);
                float4 d = *reinterpret_cast<const float4*>(hr + 512);
                float4 e = *reinterpret_cast<const float4*>(hr + 768);
                y0.x += vv.z * a.x; y0.y += vv.z * a.y; y0.z += vv.z * a.z; y0.w += vv.z * a.w;
                y1.x += vv.z * c.x; y1.y += vv.z * c.y; y1.z += vv.z * c.z; y1.w += vv.z * c.w;
                y2.x += vv.z * d.x; y2.y += vv.z * d.y; y2.z += vv.z * d.z; y2.w += vv.z * d.w;
                y3.x += vv.z * e.x; y3.y += vv.z * e.y; y3.z += vv.z * e.z; y3.w += vv.z * e.w;
            }
            {
                const float* hr = hb + (size_t)ii.w * DIM + dofs;
                float4 a = *reinterpret_cast<const float4*>(hr);
                float4 c = *reinterpret_cast<const float4*>(hr + 256);
                float4 d = *reinterpret_cast<const float4*>(hr + 512);
                float4 e = *reinterpret_cast<const float4*>(hr + 768);
                y0.x += vv.w * a.x; y0.y += vv.w * a.y; y0.z += vv.w * a.z; y0.w += vv.w * a.w;
                y1.x += vv.w * c.x; y1.y += vv.w * c.y; y1.z += vv.w * c.z; y1.w += vv.w * c.w;
                y2.x += vv.w * d.x; y2.y += vv.w * d.y; y2.z += vv.w * d.z; y2.w += vv.w * d.w;
                y3.x += vv.w * e.x; y3.y += vv.w * e.y; y3.z += vv.w * e.z; y3.w += vv.w * e.w;
            }
        }

        float* iorow = io + row * DIM + dofs;
        float4 s0 = *reinterpret_cast<const float4*>(iorow);
        float4 s1 = *reinterpret_cast<const float4*>(iorow + 256);
        float4 s2 = *reinterpret_cast<const float4*>(iorow + 512);
        float4 s3 = *reinterpret_cast<const float4*>(iorow + 768);
        float p = y0.x * s0.x + y0.y * s0.y + y0.z * s0.z + y0.w * s0.w
                + y1.x * s1.x + y1.y * s1.y + y1.z * s1.z + y1.w * s1.w
                + y2.x * s2.x + y2.y * s2.y + y2.z * s2.z + y2.w * s2.w
                + y3.x * s3.x + y3.y * s3.y + y3.z * s3.z + y3.w * s3.w;
#pragma unroll
        for (int off = 32; off; off >>= 1) p += __shfl_xor(p, off, 64);
        const float g  = 1.f / (1.f + __expf(-p));
        const float og = 1.f - g;
        float4 o0, o1, o2, o3;
        o0.x = g * y0.x + og * s0.x; o0.y = g * y0.y + og * s0.y;
        o0.z = g * y0.z + og * s0.z; o0.w = g * y0.w + og * s0.w;
        o1.x = g * y1.x + og * s1.x; o1.y = g * y1.y + og * s1.y;
        o1.z = g * y1.z + og * s1.z; o1.w = g * y1.w + og * s1.w;
        o2.x = g * y2.x + og * s2.x; o2.y = g * y2.y + og * s2.y;
        o2.z = g * y2.z + og * s2.z; o2.w = g * y2.w + og * s2.w;
        o3.x = g * y3.x + og * s3.x; o3.y = g * y3.y + og * s3.y;
        o3.z = g * y3.z + og * s3.z; o3.w = g * y3.w + og * s3.w;
        *reinterpret_cast<float4*>(iorow)       = o0;
        *reinterpret_cast<float4*>(iorow + 256) = o1;
        *reinterpret_cast<float4*>(iorow + 512) = o2;
        *reinterpret_cast<float4*>(iorow + 768) = o3;
    }
}

// ---------------------------------------------------------------------------
extern "C" void kernel_launch(void* const* d_in, const int* in_sizes, int n_in,
                              void* d_out, int out_size, void* d_ws, size_t ws_size,
                              hipStream_t stream) {
    const float* hs = (const float*)d_in[0];
    const float* W  = (const float*)d_in[1];
    float* out = (float*)d_out;

    const size_t Hfull  = (size_t)NB * SEQT * DIM;     // 8388608
    const size_t Hb     = (size_t)SEQT * DIM;          // 2097152
    const size_t Wn     = (size_t)DIM * DIM;           // 1048576
    const size_t Lf     = (size_t)NB * SEQT * KTOP;    // 524288
    const size_t SCfull = (size_t)NB * NT2 * 16384;
    const size_t SCb    = (size_t)NT2 * 16384;

    auto need = [&](size_t H, size_t SC) {
        return (2 * H + 2 * Wn) * sizeof(unsigned short) + Lf * 8 + SC * 4;
    };
    int level = (need(Hfull, SCfull) <= ws_size) ? 1
              : (need(Hfull, SCb) <= ws_size)    ? 2 : 3;

    const size_t H  = (level == 3) ? Hb : Hfull;

    unsigned short* hhi  = (unsigned short*)d_ws;
    unsigned short* hlo  = hhi + H;
    unsigned short* wthi = hlo + H;
    unsigned short* wtlo = wthi + Wn;
    float* lv = (float*)(wtlo + Wn);
    int*   li = (int*)(lv + Lf);
    float* sc = (float*)(li + Lf);

    wtrans_split<<<dim3(16, 16), dim3(256), 0, stream>>>(W, wthi, wtlo);

    if (level == 1) {
        split_bf16<<<dim3(2048), dim3(256), 0, stream>>>(hs, hhi, hlo, (int)(Hfull / 4));
        score_mfma<<<dim3(NB * NT2), dim3(256), 0, stream>>>(hhi, hlo, sc, 0);
        row_topk<<<dim3(NB * SEQT), dim3(256), 0, stream>>>(hs, sc, lv, li, 0);
        ysem_mfma<<<dim3(DIM / 128, (NB * SEQT) / 128), dim3(256), 0, stream>>>(hhi, hlo, wthi, wtlo, out);
    } else if (level == 2) {
        split_bf16<<<dim3(2048), dim3(256), 0, stream>>>(hs, hhi, hlo, (int)(Hfull / 4));
        for (int b = 0; b < NB; ++b) {
            score_mfma<<<dim3(NT2), dim3(256), 0, stream>>>(hhi, hlo, sc, b);
            row_topk<<<dim3(SEQT), dim3(256), 0, stream>>>(hs, sc, lv, li, b);
        }
        ysem_mfma<<<dim3(DIM / 128, (NB * SEQT) / 128), dim3(256), 0, stream>>>(hhi, hlo, wthi, wtlo, out);
    } else {
        for (int b = 0; b < NB; ++b) {
            split_bf16<<<dim3(512), dim3(256), 0, stream>>>(hs + (size_t)b * Hb, hhi, hlo, (int)(Hb / 4));
            score_mfma<<<dim3(NT2), dim3(256), 0, stream>>>(hhi, hlo, sc, 0);
            row_topk<<<dim3(SEQT), dim3(256), 0, stream>>>(hs, sc, lv, li, b);
            ysem_mfma<<<dim3(DIM / 128, SEQT / 128), dim3(256), 0, stream>>>(hhi, hlo, wthi, wtlo, out + (size_t)b * Hb);
        }
    }

    merge_gather<<<dim3(NB * 128), dim3(512), 0, stream>>>(hs, lv, li, out);
}

// Round 7
// 314.510 us; speedup vs baseline: 12.8735x; 1.4876x over previous
//
#include <hip/hip_runtime.h>
#include <hip/hip_bf16.h>
#include <math.h>

#define DIM    1024
#define SEQT   2048
#define NB     4
#define SCALE  0.03125f   // 1/32 = DIM^-0.5, exact power of two
#define KTOP   64
#define NT2    136        // 16*17/2 causal 128x128 tiles per batch
#define DELTA  1e-2f      // fp64-recheck window around the top-k boundary

typedef __attribute__((ext_vector_type(8))) short short8;   // 8 bf16 = 4 VGPR
typedef __attribute__((ext_vector_type(4))) float f32x4;    // MFMA C/D frag

// ---- bf16 RNE helpers (manual, deterministic) ------------------------------
__device__ __forceinline__ unsigned short bfr(float x) {
    unsigned u = __float_as_uint(x);
    unsigned r = (u + 0x7fffu + ((u >> 16) & 1u)) >> 16;
    return (unsigned short)r;
}
__device__ __forceinline__ float bf2f(unsigned short h) {
    return __uint_as_float(((unsigned)h) << 16);
}

// ---------------------------------------------------------------------------
// split_bf16: x -> hi = bf16(x), lo = bf16(x - hi)   (grid-stride, float4)
// ---------------------------------------------------------------------------
__global__ __launch_bounds__(256) void split_bf16(const float* __restrict__ x,
                                                  unsigned short* __restrict__ hi,
                                                  unsigned short* __restrict__ lo,
                                                  int n4) {
    const int stride = gridDim.x * 256;
    for (int idx = blockIdx.x * 256 + threadIdx.x; idx < n4; idx += stride) {
        float4 v = reinterpret_cast<const float4*>(x)[idx];
        ushort4 h, l;
        h.x = bfr(v.x); l.x = bfr(v.x - bf2f(h.x));
        h.y = bfr(v.y); l.y = bfr(v.y - bf2f(h.y));
        h.z = bfr(v.z); l.z = bfr(v.z - bf2f(h.z));
        h.w = bfr(v.w); l.w = bfr(v.w - bf2f(h.w));
        reinterpret_cast<ushort4*>(hi)[idx] = h;
        reinterpret_cast<ushort4*>(lo)[idx] = l;
    }
}

// ---------------------------------------------------------------------------
// wtrans_split: Wt[n][k] = W[k][n] as hi/lo bf16 (64x64 LDS tile transpose)
// ---------------------------------------------------------------------------
__global__ __launch_bounds__(256) void wtrans_split(const float* __restrict__ W,
                                                    unsigned short* __restrict__ thi,
                                                    unsigned short* __restrict__ tlo) {
    __shared__ float tle[64][65];
    const int n0 = blockIdx.x * 64, k0 = blockIdx.y * 64;
    const int tid = threadIdx.x;
    const int r = tid >> 2, c0 = (tid & 3) * 16;
#pragma unroll
    for (int s = 0; s < 16; s += 4) {
        float4 v = *reinterpret_cast<const float4*>(&W[(size_t)(k0 + r) * DIM + n0 + c0 + s]);
        tle[r][c0 + s + 0] = v.x; tle[r][c0 + s + 1] = v.y;
        tle[r][c0 + s + 2] = v.z; tle[r][c0 + s + 3] = v.w;
    }
    __syncthreads();
#pragma unroll
    for (int s = 0; s < 16; s += 4) {
        float a0 = tle[c0 + s + 0][r];
        float a1 = tle[c0 + s + 1][r];
        float a2 = tle[c0 + s + 2][r];
        float a3 = tle[c0 + s + 3][r];
        ushort4 h, l;
        h.x = bfr(a0); l.x = bfr(a0 - bf2f(h.x));
        h.y = bfr(a1); l.y = bfr(a1 - bf2f(h.y));
        h.z = bfr(a2); l.z = bfr(a2 - bf2f(h.z));
        h.w = bfr(a3); l.w = bfr(a3 - bf2f(h.w));
        *reinterpret_cast<ushort4*>(&thi[(size_t)(n0 + r) * DIM + k0 + c0 + s]) = h;
        *reinterpret_cast<ushort4*>(&tlo[(size_t)(n0 + r) * DIM + k0 + c0 + s]) = l;
    }
}

// ---------------------------------------------------------------------------
// score_mfma: causal 128x128 score tiles via bf16 split-3 MFMA, -inf masked.
// ---------------------------------------------------------------------------
__global__ __launch_bounds__(256) void score_mfma(const unsigned short* __restrict__ hhi,
                                                  const unsigned short* __restrict__ hlo,
                                                  float* __restrict__ sc, int b0) {
    const int bl = blockIdx.x / NT2;
    const int t  = blockIdx.x % NT2;
    const int b  = b0 + bl;
    int qt = (int)((sqrtf(8.f * t + 1.f) - 1.f) * 0.5f);
    while ((qt + 1) * (qt + 2) / 2 <= t) ++qt;
    while (qt * (qt + 1) / 2 > t) --qt;
    const int kt = t - qt * (qt + 1) / 2;

    const size_t base = (size_t)b * SEQT * DIM;
    const unsigned short* Ah = hhi + base + (size_t)(qt * 128) * DIM;
    const unsigned short* Al = hlo + base + (size_t)(qt * 128) * DIM;
    const unsigned short* Bh = hhi + base + (size_t)(kt * 128) * DIM;
    const unsigned short* Bl = hlo + base + (size_t)(kt * 128) * DIM;

    __shared__ unsigned short lds[4][128][40];   // Ahi, Alo, Bhi, Blo ; 40KB

    const int tid  = threadIdx.x;
    const int lane = tid & 63, wid = tid >> 6;
    const int wr = (wid >> 1) * 64, wc = (wid & 1) * 64;
    const int fr = lane & 15, fc = lane >> 4;

    const int sr  = tid >> 2;
    const int scg = (tid & 3) * 8;

    f32x4 acc[4][4];
    const f32x4 zz = {0.f, 0.f, 0.f, 0.f};
#pragma unroll
    for (int i = 0; i < 4; ++i)
#pragma unroll
        for (int j = 0; j < 4; ++j) acc[i][j] = zz;

    for (int k0 = 0; k0 < DIM; k0 += 32) {
        int4 va0 = *reinterpret_cast<const int4*>(Ah + (size_t)sr * DIM + k0 + scg);
        int4 va1 = *reinterpret_cast<const int4*>(Ah + (size_t)(sr + 64) * DIM + k0 + scg);
        int4 va2 = *reinterpret_cast<const int4*>(Al + (size_t)sr * DIM + k0 + scg);
        int4 va3 = *reinterpret_cast<const int4*>(Al + (size_t)(sr + 64) * DIM + k0 + scg);
        int4 vb0 = *reinterpret_cast<const int4*>(Bh + (size_t)sr * DIM + k0 + scg);
        int4 vb1 = *reinterpret_cast<const int4*>(Bh + (size_t)(sr + 64) * DIM + k0 + scg);
        int4 vb2 = *reinterpret_cast<const int4*>(Bl + (size_t)sr * DIM + k0 + scg);
        int4 vb3 = *reinterpret_cast<const int4*>(Bl + (size_t)(sr + 64) * DIM + k0 + scg);
        __syncthreads();
        *reinterpret_cast<int4*>(&lds[0][sr][scg])      = va0;
        *reinterpret_cast<int4*>(&lds[0][sr + 64][scg]) = va1;
        *reinterpret_cast<int4*>(&lds[1][sr][scg])      = va2;
        *reinterpret_cast<int4*>(&lds[1][sr + 64][scg]) = va3;
        *reinterpret_cast<int4*>(&lds[2][sr][scg])      = vb0;
        *reinterpret_cast<int4*>(&lds[2][sr + 64][scg]) = vb1;
        *reinterpret_cast<int4*>(&lds[3][sr][scg])      = vb2;
        *reinterpret_cast<int4*>(&lds[3][sr + 64][scg]) = vb3;
        __syncthreads();

        short8 ah[4], al4[4], bh4[4], bl4[4];
#pragma unroll
        for (int f = 0; f < 4; ++f) {
            ah[f]  = *reinterpret_cast<const short8*>(&lds[0][wr + f * 16 + fr][fc * 8]);
            al4[f] = *reinterpret_cast<const short8*>(&lds[1][wr + f * 16 + fr][fc * 8]);
            bh4[f] = *reinterpret_cast<const short8*>(&lds[2][wc + f * 16 + fr][fc * 8]);
            bl4[f] = *reinterpret_cast<const short8*>(&lds[3][wc + f * 16 + fr][fc * 8]);
        }
#pragma unroll
        for (int i = 0; i < 4; ++i)
#pragma unroll
            for (int j = 0; j < 4; ++j) {
                acc[i][j] = __builtin_amdgcn_mfma_f32_16x16x32_bf16(ah[i],  bh4[j], acc[i][j], 0, 0, 0);
                acc[i][j] = __builtin_amdgcn_mfma_f32_16x16x32_bf16(ah[i],  bl4[j], acc[i][j], 0, 0, 0);
                acc[i][j] = __builtin_amdgcn_mfma_f32_16x16x32_bf16(al4[i], bh4[j], acc[i][j], 0, 0, 0);
            }
    }

    float* tile = sc + ((size_t)bl * NT2 + t) * 16384;
    const bool diag = (qt == kt);
#pragma unroll
    for (int i = 0; i < 4; ++i)
#pragma unroll
        for (int j = 0; j < 4; ++j)
#pragma unroll
            for (int v = 0; v < 4; ++v) {
                const int row = wr + i * 16 + fc * 4 + v;
                const int col = wc + j * 16 + fr;
                float val = acc[i][j][v] * SCALE;
                if (diag && col >= row) val = -INFINITY;
                tile[row * 128 + col] = val;
            }
}

// ---------------------------------------------------------------------------
// ysem_mfma: C = SCALE * A @ W via bf16 split-3 MFMA; B given transposed.
// ---------------------------------------------------------------------------
__global__ __launch_bounds__(256) void ysem_mfma(const unsigned short* __restrict__ ahi,
                                                 const unsigned short* __restrict__ alo,
                                                 const unsigned short* __restrict__ wthi,
                                                 const unsigned short* __restrict__ wtlo,
                                                 float* __restrict__ C) {
    const int n0 = blockIdx.x * 128;
    const int m0 = blockIdx.y * 128;
    const unsigned short* Ah = ahi + (size_t)m0 * DIM;
    const unsigned short* Al = alo + (size_t)m0 * DIM;
    const unsigned short* Bh = wthi + (size_t)n0 * DIM;
    const unsigned short* Bl = wtlo + (size_t)n0 * DIM;

    __shared__ unsigned short lds[4][128][40];

    const int tid  = threadIdx.x;
    const int lane = tid & 63, wid = tid >> 6;
    const int wr = (wid >> 1) * 64, wc = (wid & 1) * 64;
    const int fr = lane & 15, fc = lane >> 4;
    const int sr  = tid >> 2;
    const int scg = (tid & 3) * 8;

    f32x4 acc[4][4];
    const f32x4 zz = {0.f, 0.f, 0.f, 0.f};
#pragma unroll
    for (int i = 0; i < 4; ++i)
#pragma unroll
        for (int j = 0; j < 4; ++j) acc[i][j] = zz;

    for (int k0 = 0; k0 < DIM; k0 += 32) {
        int4 va0 = *reinterpret_cast<const int4*>(Ah + (size_t)sr * DIM + k0 + scg);
        int4 va1 = *reinterpret_cast<const int4*>(Ah + (size_t)(sr + 64) * DIM + k0 + scg);
        int4 va2 = *reinterpret_cast<const int4*>(Al + (size_t)sr * DIM + k0 + scg);
        int4 va3 = *reinterpret_cast<const int4*>(Al + (size_t)(sr + 64) * DIM + k0 + scg);
        int4 vb0 = *reinterpret_cast<const int4*>(Bh + (size_t)sr * DIM + k0 + scg);
        int4 vb1 = *reinterpret_cast<const int4*>(Bh + (size_t)(sr + 64) * DIM + k0 + scg);
        int4 vb2 = *reinterpret_cast<const int4*>(Bl + (size_t)sr * DIM + k0 + scg);
        int4 vb3 = *reinterpret_cast<const int4*>(Bl + (size_t)(sr + 64) * DIM + k0 + scg);
        __syncthreads();
        *reinterpret_cast<int4*>(&lds[0][sr][scg])      = va0;
        *reinterpret_cast<int4*>(&lds[0][sr + 64][scg]) = va1;
        *reinterpret_cast<int4*>(&lds[1][sr][scg])      = va2;
        *reinterpret_cast<int4*>(&lds[1][sr + 64][scg]) = va3;
        *reinterpret_cast<int4*>(&lds[2][sr][scg])      = vb0;
        *reinterpret_cast<int4*>(&lds[2][sr + 64][scg]) = vb1;
        *reinterpret_cast<int4*>(&lds[3][sr][scg])      = vb2;
        *reinterpret_cast<int4*>(&lds[3][sr + 64][scg]) = vb3;
        __syncthreads();

        short8 ah[4], al4[4], bh4[4], bl4[4];
#pragma unroll
        for (int f = 0; f < 4; ++f) {
            ah[f]  = *reinterpret_cast<const short8*>(&lds[0][wr + f * 16 + fr][fc * 8]);
            al4[f] = *reinterpret_cast<const short8*>(&lds[1][wr + f * 16 + fr][fc * 8]);
            bh4[f] = *reinterpret_cast<const short8*>(&lds[2][wc + f * 16 + fr][fc * 8]);
            bl4[f] = *reinterpret_cast<const short8*>(&lds[3][wc + f * 16 + fr][fc * 8]);
        }
#pragma unroll
        for (int i = 0; i < 4; ++i)
#pragma unroll
            for (int j = 0; j < 4; ++j) {
                acc[i][j] = __builtin_amdgcn_mfma_f32_16x16x32_bf16(ah[i],  bh4[j], acc[i][j], 0, 0, 0);
                acc[i][j] = __builtin_amdgcn_mfma_f32_16x16x32_bf16(ah[i],  bl4[j], acc[i][j], 0, 0, 0);
                acc[i][j] = __builtin_amdgcn_mfma_f32_16x16x32_bf16(al4[i], bh4[j], acc[i][j], 0, 0, 0);
            }
    }

#pragma unroll
    for (int i = 0; i < 4; ++i)
#pragma unroll
        for (int j = 0; j < 4; ++j)
#pragma unroll
            for (int v = 0; v < 4; ++v) {
                const int row = wr + i * 16 + fc * 4 + v;
                const int col = wc + j * 16 + fr;
                C[(size_t)(m0 + row) * DIM + n0 + col] = acc[i][j][v] * SCALE;
            }
}

// ---------------------------------------------------------------------------
// Kernel 3: exact top-64 per row via 11-bit radix histogram + tie ranking,
// then fp64 re-check of boundary-window candidates (matches np fp64 top-k).
// ---------------------------------------------------------------------------
__device__ __forceinline__ unsigned flipf(float v) {
    unsigned bu = __float_as_uint(v);
    return bu ^ ((unsigned)((int)bu >> 31) | 0x80000000u);
}

__global__ __launch_bounds__(256) void row_topk(const float* __restrict__ hs,
                                                const float* __restrict__ sc,
                                                float* __restrict__ lv,
                                                int* __restrict__ li, int b0) {
    const int bl = blockIdx.x >> 11;
    const int i  = blockIdx.x & 2047;
    const int b  = b0 + bl;
    const int tid = threadIdx.x;

    float* outv = lv + (((size_t)b * SEQT + i) << 6);
    int*   outi = li + (((size_t)b * SEQT + i) << 6);
    const size_t batch_off = (size_t)bl * NT2 * 16384;

    if (i <= KTOP) {
        if (tid < KTOP) {
            float v = 0.f;
            int   ix = 0;
            if (tid < i) {
                v  = sc[batch_off + (size_t)i * 128 + tid];
                ix = tid;
            }
            outv[tid] = v;
            outi[tid] = ix;
        }
        return;
    }

    const int qt = i >> 7, r = i & 127;
    const int nscan = (qt + 1) * 128;
    const size_t rowb = batch_off + ((size_t)(qt * (qt + 1) / 2)) * 16384 + (size_t)r * 128;

    float    ev[8];
    unsigned eu[8];
#pragma unroll
    for (int s = 0; s < 8; ++s) {
        const int j = tid + (s << 8);
        ev[s] = (j < nscan) ? sc[rowb + ((size_t)(j >> 7)) * 16384 + (j & 127)] : -INFINITY;
        eu[s] = flipf(ev[s]);
    }

    __shared__ int hist[2048];
    __shared__ int part[256];
    __shared__ int sB, sM;
    for (int h = tid; h < 2048; h += 256) hist[h] = 0;
    __syncthreads();
#pragma unroll
    for (int s = 0; s < 8; ++s) atomicAdd(&hist[eu[s] >> 21], 1);
    __syncthreads();
    {
        int ps = 0;
#pragma unroll
        for (int h = 0; h < 8; ++h) ps += hist[tid * 8 + h];
        part[tid] = ps;
    }
    __syncthreads();
    if (tid == 0) {
        int acc = 0;
        int g = 255;
        for (; g > 0; --g) {
            if (acc + part[g] >= KTOP) break;
            acc += part[g];
        }
        int B = g * 8;
        for (int h = g * 8 + 7; h >= g * 8; --h) {
            if (acc + hist[h] >= KTOP) { B = h; break; }
            acc += hist[h];
        }
        sB = B;
        sM = acc;
    }
    __syncthreads();
    const unsigned B = (unsigned)sB;
    const int m = sM;
    const int tn = KTOP - m;

    __shared__ unsigned cu[512];
    __shared__ float    cva[512];
    __shared__ int      cix[512];
    __shared__ int      ccnt;
    __shared__ float    lsv[64];
    if (tid == 0) ccnt = 0;
    __syncthreads();
#pragma unroll
    for (int s = 0; s < 8; ++s) {
        if ((eu[s] >> 21) == B) {
            int p = atomicAdd(&ccnt, 1);
            if (p < 512) { cu[p] = eu[s]; cva[p] = ev[s]; cix[p] = tid + (s << 8); }
        }
    }
    __syncthreads();
    const int cb = (ccnt < 512) ? ccnt : 512;

    for (int c = tid; c < cb; c += 256) {
        const unsigned u = cu[c];
        const int ix = cix[c];
        int rk = 0;
        for (int c2 = 0; c2 < cb; ++c2) {
            const unsigned u2 = cu[c2];
            rk += (u2 > u) || (u2 == u && cix[c2] < ix);
        }
        if (rk < tn) { outv[m + rk] = cva[c]; outi[m + rk] = ix; lsv[m + rk] = cva[c]; }
    }

    __shared__ int ocnt;
    if (tid == 0) ocnt = 0;
    __syncthreads();
#pragma unroll
    for (int s = 0; s < 8; ++s) {
        if ((eu[s] >> 21) > B) {
            int p = atomicAdd(&ocnt, 1);
            outv[p] = ev[s];
            outi[p] = tid + (s << 8);
            lsv[p]  = ev[s];
        }
    }

    // ---------------- fp64 boundary fixup ----------------
    __shared__ float  svmin;
    __shared__ int    tcnt;
    __shared__ int    spos[64];
    __shared__ double dval[256];
    __syncthreads();
    if (tid == 0) {
        float mv = lsv[0];
        for (int k = 1; k < KTOP; ++k) mv = fminf(mv, lsv[k]);
        svmin = mv;
        ccnt = 0;
        tcnt = 0;
    }
    __syncthreads();
    const float vmin = svmin;
#pragma unroll
    for (int s = 0; s < 8; ++s) {
        const int j = tid + (s << 8);
        if (j < nscan && fabsf(ev[s] - vmin) <= DELTA) {
            int p = atomicAdd(&ccnt, 1);
            if (p < 256) { cva[p] = ev[s]; cix[p] = j; }
        }
    }
    __syncthreads();
    const int mb = ccnt;
    if (mb < 2 || mb > 256) return;

    if (tid < KTOP && fabsf(lsv[tid] - vmin) <= DELTA) {
        int q = atomicAdd(&tcnt, 1);
        spos[q] = tid;
    }
    __syncthreads();
    const int t = tcnt;

    const int wid = tid >> 6, lane = tid & 63;
    const float* qrow = hs + ((size_t)b * SEQT + i) * DIM;
    for (int c = wid; c < mb; c += 4) {
        const float* krow = hs + ((size_t)b * SEQT + cix[c]) * DIM;
        double acc = 0.0;
        for (int d = lane; d < DIM; d += 64)
            acc += (double)qrow[d] * (double)krow[d];
#pragma unroll
        for (int off = 32; off; off >>= 1) acc += __shfl_xor(acc, off, 64);
        if (lane == 0) dval[c] = acc;
    }
    __syncthreads();

    if (tid < mb) {
        const double dv = dval[tid];
        const int ix = cix[tid];
        int rk = 0;
        for (int c2 = 0; c2 < mb; ++c2)
            rk += (dval[c2] > dv) || (dval[c2] == dv && cix[c2] < ix);
        if (rk < t) {
            const int pp = spos[rk];
            outv[pp] = cva[tid];
            outi[pp] = ix;
        }
    }
}

// ---------------------------------------------------------------------------
// Kernel 4 (levels 1-2): gather y_episodic from bf16-hi rows (L2-resident),
// gate, final output. XCD-batch affinity: batch = (blockIdx%8)>>1 so each
// XCD's gather working set is one batch's 4MB bf16 array (fits 4MB L2).
// 1024 blocks x 8 waves; one row per wave; lane owns dims {l*8..l*8+7,
// 512+l*8..+7} -> every wave load is a contiguous 1KB access.
// ---------------------------------------------------------------------------
__global__ __launch_bounds__(512) void gather_bf16(const unsigned short* __restrict__ hhi,
                                                   const float* __restrict__ lv,
                                                   const int* __restrict__ li,
                                                   float* __restrict__ io) {
    const int tid  = threadIdx.x;
    const int lane = tid & 63;
    const int wid  = tid >> 6;
    const int blk  = blockIdx.x;
    const int xs   = blk & 7;                       // ~XCD slot
    const int b    = xs >> 1;                       // batch per XCD pair
    const int rg   = (blk >> 3) * 2 + (xs & 1);     // 0..255
    const int i    = rg * 8 + wid;                  // row in batch

    const size_t row = (size_t)b * SEQT + i;
    const float4* v4 = reinterpret_cast<const float4*>(lv + (row << 6));
    const int4*   i4 = reinterpret_cast<const int4*>(li + (row << 6));
    const unsigned short* hb = hhi + (size_t)b * SEQT * DIM;
    const int d0 = lane * 8;

    float y[16];
#pragma unroll
    for (int t = 0; t < 16; ++t) y[t] = 0.f;

#pragma unroll 2
    for (int kk = 0; kk < 16; ++kk) {
        const float4 vv = v4[kk];
        const int4   ii = i4[kk];
        const float  vs[4] = {vv.x, vv.y, vv.z, vv.w};
        const int    js[4] = {ii.x, ii.y, ii.z, ii.w};
#pragma unroll
        for (int c = 0; c < 4; ++c) {
            const float v = vs[c];
            const unsigned short* hr = hb + (size_t)js[c] * DIM + d0;
            uint4 w0 = *reinterpret_cast<const uint4*>(hr);
            uint4 w1 = *reinterpret_cast<const uint4*>(hr + 512);
            const unsigned wa[8] = {w0.x, w0.y, w0.z, w0.w, w1.x, w1.y, w1.z, w1.w};
#pragma unroll
            for (int e = 0; e < 8; ++e) {
                float flo = __uint_as_float(wa[e] << 16);
                float fhi = __uint_as_float(wa[e] & 0xffff0000u);
                y[2 * e + 0] += v * flo;
                y[2 * e + 1] += v * fhi;
            }
        }
    }

    float* iorow = io + row * DIM;
    float4 s0 = *reinterpret_cast<const float4*>(iorow + d0);
    float4 s1 = *reinterpret_cast<const float4*>(iorow + d0 + 4);
    float4 s2 = *reinterpret_cast<const float4*>(iorow + 512 + d0);
    float4 s3 = *reinterpret_cast<const float4*>(iorow + 512 + d0 + 4);
    const float ss[16] = {s0.x, s0.y, s0.z, s0.w, s1.x, s1.y, s1.z, s1.w,
                          s2.x, s2.y, s2.z, s2.w, s3.x, s3.y, s3.z, s3.w};
    float p = 0.f;
#pragma unroll
    for (int t = 0; t < 16; ++t) p += y[t] * ss[t];
#pragma unroll
    for (int off = 32; off; off >>= 1) p += __shfl_xor(p, off, 64);
    const float g  = 1.f / (1.f + __expf(-p));
    const float og = 1.f - g;
    float o[16];
#pragma unroll
    for (int t = 0; t < 16; ++t) o[t] = g * y[t] + og * ss[t];
    *reinterpret_cast<float4*>(iorow + d0)           = *reinterpret_cast<float4*>(&o[0]);
    *reinterpret_cast<float4*>(iorow + d0 + 4)       = *reinterpret_cast<float4*>(&o[4]);
    *reinterpret_cast<float4*>(iorow + 512 + d0)     = *reinterpret_cast<float4*>(&o[8]);
    *reinterpret_cast<float4*>(iorow + 512 + d0 + 4) = *reinterpret_cast<float4*>(&o[12]);
}

// ---------------------------------------------------------------------------
// Kernel 4 (level-3 fallback): fp32 gather (hhi holds only one batch there).
// ---------------------------------------------------------------------------
__global__ __launch_bounds__(512) void merge_gather(const float* __restrict__ hs,
                                                    const float* __restrict__ lv,
                                                    const int* __restrict__ li,
                                                    float* __restrict__ io) {
    const int tid  = threadIdx.x;
    const int lane = tid & 63;
    const int wid  = tid >> 6;
    const int b    = blockIdx.x >> 7;
    const int r0   = (blockIdx.x & 127) * 16;
    const float* hb = hs + (size_t)b * SEQT * DIM;
    const int dofs = lane * 4;

    for (int rr = wid; rr < 16; rr += 8) {
        const int i = r0 + rr;
        const size_t row = (size_t)b * SEQT + i;
        const float4* v4 = reinterpret_cast<const float4*>(lv + (row << 6));
        const int4*   i4 = reinterpret_cast<const int4*>(li + (row << 6));

        float4 y0 = {0.f, 0.f, 0.f, 0.f}, y1 = y0, y2 = y0, y3 = y0;
#pragma unroll 4
        for (int kk = 0; kk < 16; ++kk) {
            const float4 vv = v4[kk];
            const int4   ii = i4[kk];
            const float  vs[4] = {vv.x, vv.y, vv.z, vv.w};
            const int    js[4] = {ii.x, ii.y, ii.z, ii.w};
#pragma unroll
            for (int c = 0; c < 4; ++c) {
                const float v = vs[c];
                const float* hr = hb + (size_t)js[c] * DIM + dofs;
                float4 a = *reinterpret_cast<const float4*>(hr);
                float4 cc = *reinterpret_cast<const float4*>(hr + 256);
                float4 d = *reinterpret_cast<const float4*>(hr + 512);
                float4 e = *reinterpret_cast<const float4*>(hr + 768);
                y0.x += v * a.x;  y0.y += v * a.y;  y0.z += v * a.z;  y0.w += v * a.w;
                y1.x += v * cc.x; y1.y += v * cc.y; y1.z += v * cc.z; y1.w += v * cc.w;
                y2.x += v * d.x;  y2.y += v * d.y;  y2.z += v * d.z;  y2.w += v * d.w;
                y3.x += v * e.x;  y3.y += v * e.y;  y3.z += v * e.z;  y3.w += v * e.w;
            }
        }

        float* iorow = io + row * DIM + dofs;
        float4 s0 = *reinterpret_cast<const float4*>(iorow);
        float4 s1 = *reinterpret_cast<const float4*>(iorow + 256);
        float4 s2 = *reinterpret_cast<const float4*>(iorow + 512);
        float4 s3 = *reinterpret_cast<const float4*>(iorow + 768);
        float p = y0.x * s0.x + y0.y * s0.y + y0.z * s0.z + y0.w * s0.w
                + y1.x * s1.x + y1.y * s1.y + y1.z * s1.z + y1.w * s1.w
                + y2.x * s2.x + y2.y * s2.y + y2.z * s2.z + y2.w * s2.w
                + y3.x * s3.x + y3.y * s3.y + y3.z * s3.z + y3.w * s3.w;
#pragma unroll
        for (int off = 32; off; off >>= 1) p += __shfl_xor(p, off, 64);
        const float g  = 1.f / (1.f + __expf(-p));
        const float og = 1.f - g;
        float4 o0, o1, o2, o3;
        o0.x = g * y0.x + og * s0.x; o0.y = g * y0.y + og * s0.y;
        o0.z = g * y0.z + og * s0.z; o0.w = g * y0.w + og * s0.w;
        o1.x = g * y1.x + og * s1.x; o1.y = g * y1.y + og * s1.y;
        o1.z = g * y1.z + og * s1.z; o1.w = g * y1.w + og * s1.w;
        o2.x = g * y2.x + og * s2.x; o2.y = g * y2.y + og * s2.y;
        o2.z = g * y2.z + og * s2.z; o2.w = g * y2.w + og * s2.w;
        o3.x = g * y3.x + og * s3.x; o3.y = g * y3.y + og * s3.y;
        o3.z = g * y3.z + og * s3.z; o3.w = g * y3.w + og * s3.w;
        *reinterpret_cast<float4*>(iorow)       = o0;
        *reinterpret_cast<float4*>(iorow + 256) = o1;
        *reinterpret_cast<float4*>(iorow + 512) = o2;
        *reinterpret_cast<float4*>(iorow + 768) = o3;
    }
}

// ---------------------------------------------------------------------------
extern "C" void kernel_launch(void* const* d_in, const int* in_sizes, int n_in,
                              void* d_out, int out_size, void* d_ws, size_t ws_size,
                              hipStream_t stream) {
    const float* hs = (const float*)d_in[0];
    const float* W  = (const float*)d_in[1];
    float* out = (float*)d_out;

    const size_t Hfull  = (size_t)NB * SEQT * DIM;     // 8388608
    const size_t Hb     = (size_t)SEQT * DIM;          // 2097152
    const size_t Wn     = (size_t)DIM * DIM;           // 1048576
    const size_t Lf     = (size_t)NB * SEQT * KTOP;    // 524288
    const size_t SCfull = (size_t)NB * NT2 * 16384;
    const size_t SCb    = (size_t)NT2 * 16384;

    auto need = [&](size_t H, size_t SC) {
        return (2 * H + 2 * Wn) * sizeof(unsigned short) + Lf * 8 + SC * 4;
    };
    int level = (need(Hfull, SCfull) <= ws_size) ? 1
              : (need(Hfull, SCb) <= ws_size)    ? 2 : 3;

    const size_t H  = (level == 3) ? Hb : Hfull;

    unsigned short* hhi  = (unsigned short*)d_ws;
    unsigned short* hlo  = hhi + H;
    unsigned short* wthi = hlo + H;
    unsigned short* wtlo = wthi + Wn;
    float* lv = (float*)(wtlo + Wn);
    int*   li = (int*)(lv + Lf);
    float* sc = (float*)(li + Lf);

    wtrans_split<<<dim3(16, 16), dim3(256), 0, stream>>>(W, wthi, wtlo);

    if (level == 1) {
        split_bf16<<<dim3(2048), dim3(256), 0, stream>>>(hs, hhi, hlo, (int)(Hfull / 4));
        score_mfma<<<dim3(NB * NT2), dim3(256), 0, stream>>>(hhi, hlo, sc, 0);
        row_topk<<<dim3(NB * SEQT), dim3(256), 0, stream>>>(hs, sc, lv, li, 0);
        ysem_mfma<<<dim3(DIM / 128, (NB * SEQT) / 128), dim3(256), 0, stream>>>(hhi, hlo, wthi, wtlo, out);
        gather_bf16<<<dim3(1024), dim3(512), 0, stream>>>(hhi, lv, li, out);
    } else if (level == 2) {
        split_bf16<<<dim3(2048), dim3(256), 0, stream>>>(hs, hhi, hlo, (int)(Hfull / 4));
        for (int b = 0; b < NB; ++b) {
            score_mfma<<<dim3(NT2), dim3(256), 0, stream>>>(hhi, hlo, sc, b);
            row_topk<<<dim3(SEQT), dim3(256), 0, stream>>>(hs, sc, lv, li, b);
        }
        ysem_mfma<<<dim3(DIM / 128, (NB * SEQT) / 128), dim3(256), 0, stream>>>(hhi, hlo, wthi, wtlo, out);
        gather_bf16<<<dim3(1024), dim3(512), 0, stream>>>(hhi, lv, li, out);
    } else {
        for (int b = 0; b < NB; ++b) {
            split_bf16<<<dim3(512), dim3(256), 0, stream>>>(hs + (size_t)b * Hb, hhi, hlo, (int)(Hb / 4));
            score_mfma<<<dim3(NT2), dim3(256), 0, stream>>>(hhi, hlo, sc, 0);
            row_topk<<<dim3(SEQT), dim3(256), 0, stream>>>(hs, sc, lv, li, b);
            ysem_mfma<<<dim3(DIM / 128, SEQT / 128), dim3(256), 0, stream>>>(hhi, hlo, wthi, wtlo, out + (size_t)b * Hb);
        }
        merge_gather<<<dim3(NB * 128), dim3(512), 0, stream>>>(hs, lv, li, out);
    }
}

// Round 8
// 284.614 us; speedup vs baseline: 14.2257x; 1.1050x over previous
//
#include <hip/hip_runtime.h>
#include <hip/hip_bf16.h>
#include <math.h>

#define DIM    1024
#define SEQT   2048
#define NB     4
#define SCALE  0.03125f   // 1/32 = DIM^-0.5, exact power of two
#define KTOP   64
#define NT2    136        // 16*17/2 causal 128x128 tiles per batch
#define DELTA  1e-2f      // fp64-recheck window around the top-k boundary

typedef __attribute__((ext_vector_type(8))) short short8;   // 8 bf16 = 4 VGPR
typedef __attribute__((ext_vector_type(4))) float f32x4;    // MFMA C/D frag

// ---- bf16 RNE helpers (manual, deterministic) ------------------------------
__device__ __forceinline__ unsigned short bfr(float x) {
    unsigned u = __float_as_uint(x);
    unsigned r = (u + 0x7fffu + ((u >> 16) & 1u)) >> 16;
    return (unsigned short)r;
}
__device__ __forceinline__ float bf2f(unsigned short h) {
    return __uint_as_float(((unsigned)h) << 16);
}

// ---------------------------------------------------------------------------
// split_bf16: x -> hi = bf16(x), lo = bf16(x - hi)   (grid-stride, float4)
// ---------------------------------------------------------------------------
__global__ __launch_bounds__(256) void split_bf16(const float* __restrict__ x,
                                                  unsigned short* __restrict__ hi,
                                                  unsigned short* __restrict__ lo,
                                                  int n4) {
    const int stride = gridDim.x * 256;
    for (int idx = blockIdx.x * 256 + threadIdx.x; idx < n4; idx += stride) {
        float4 v = reinterpret_cast<const float4*>(x)[idx];
        ushort4 h, l;
        h.x = bfr(v.x); l.x = bfr(v.x - bf2f(h.x));
        h.y = bfr(v.y); l.y = bfr(v.y - bf2f(h.y));
        h.z = bfr(v.z); l.z = bfr(v.z - bf2f(h.z));
        h.w = bfr(v.w); l.w = bfr(v.w - bf2f(h.w));
        reinterpret_cast<ushort4*>(hi)[idx] = h;
        reinterpret_cast<ushort4*>(lo)[idx] = l;
    }
}

// ---------------------------------------------------------------------------
// wtrans_split: Wt[n][k] = W[k][n] as hi/lo bf16 (64x64 LDS tile transpose)
// ---------------------------------------------------------------------------
__global__ __launch_bounds__(256) void wtrans_split(const float* __restrict__ W,
                                                    unsigned short* __restrict__ thi,
                                                    unsigned short* __restrict__ tlo) {
    __shared__ float tle[64][65];
    const int n0 = blockIdx.x * 64, k0 = blockIdx.y * 64;
    const int tid = threadIdx.x;
    const int r = tid >> 2, c0 = (tid & 3) * 16;
#pragma unroll
    for (int s = 0; s < 16; s += 4) {
        float4 v = *reinterpret_cast<const float4*>(&W[(size_t)(k0 + r) * DIM + n0 + c0 + s]);
        tle[r][c0 + s + 0] = v.x; tle[r][c0 + s + 1] = v.y;
        tle[r][c0 + s + 2] = v.z; tle[r][c0 + s + 3] = v.w;
    }
    __syncthreads();
#pragma unroll
    for (int s = 0; s < 16; s += 4) {
        float a0 = tle[c0 + s + 0][r];
        float a1 = tle[c0 + s + 1][r];
        float a2 = tle[c0 + s + 2][r];
        float a3 = tle[c0 + s + 3][r];
        ushort4 h, l;
        h.x = bfr(a0); l.x = bfr(a0 - bf2f(h.x));
        h.y = bfr(a1); l.y = bfr(a1 - bf2f(h.y));
        h.z = bfr(a2); l.z = bfr(a2 - bf2f(h.z));
        h.w = bfr(a3); l.w = bfr(a3 - bf2f(h.w));
        *reinterpret_cast<ushort4*>(&thi[(size_t)(n0 + r) * DIM + k0 + c0 + s]) = h;
        *reinterpret_cast<ushort4*>(&tlo[(size_t)(n0 + r) * DIM + k0 + c0 + s]) = l;
    }
}

// ---------------------------------------------------------------------------
// score_mfma: causal 128x128 score tiles via bf16 split-3 MFMA, -inf masked.
// ---------------------------------------------------------------------------
__global__ __launch_bounds__(256) void score_mfma(const unsigned short* __restrict__ hhi,
                                                  const unsigned short* __restrict__ hlo,
                                                  float* __restrict__ sc, int b0) {
    const int bl = blockIdx.x / NT2;
    const int t  = blockIdx.x % NT2;
    const int b  = b0 + bl;
    int qt = (int)((sqrtf(8.f * t + 1.f) - 1.f) * 0.5f);
    while ((qt + 1) * (qt + 2) / 2 <= t) ++qt;
    while (qt * (qt + 1) / 2 > t) --qt;
    const int kt = t - qt * (qt + 1) / 2;

    const size_t base = (size_t)b * SEQT * DIM;
    const unsigned short* Ah = hhi + base + (size_t)(qt * 128) * DIM;
    const unsigned short* Al = hlo + base + (size_t)(qt * 128) * DIM;
    const unsigned short* Bh = hhi + base + (size_t)(kt * 128) * DIM;
    const unsigned short* Bl = hlo + base + (size_t)(kt * 128) * DIM;

    __shared__ unsigned short lds[4][128][40];   // Ahi, Alo, Bhi, Blo ; 40KB

    const int tid  = threadIdx.x;
    const int lane = tid & 63, wid = tid >> 6;
    const int wr = (wid >> 1) * 64, wc = (wid & 1) * 64;
    const int fr = lane & 15, fc = lane >> 4;

    const int sr  = tid >> 2;
    const int scg = (tid & 3) * 8;

    f32x4 acc[4][4];
    const f32x4 zz = {0.f, 0.f, 0.f, 0.f};
#pragma unroll
    for (int i = 0; i < 4; ++i)
#pragma unroll
        for (int j = 0; j < 4; ++j) acc[i][j] = zz;

    for (int k0 = 0; k0 < DIM; k0 += 32) {
        int4 va0 = *reinterpret_cast<const int4*>(Ah + (size_t)sr * DIM + k0 + scg);
        int4 va1 = *reinterpret_cast<const int4*>(Ah + (size_t)(sr + 64) * DIM + k0 + scg);
        int4 va2 = *reinterpret_cast<const int4*>(Al + (size_t)sr * DIM + k0 + scg);
        int4 va3 = *reinterpret_cast<const int4*>(Al + (size_t)(sr + 64) * DIM + k0 + scg);
        int4 vb0 = *reinterpret_cast<const int4*>(Bh + (size_t)sr * DIM + k0 + scg);
        int4 vb1 = *reinterpret_cast<const int4*>(Bh + (size_t)(sr + 64) * DIM + k0 + scg);
        int4 vb2 = *reinterpret_cast<const int4*>(Bl + (size_t)sr * DIM + k0 + scg);
        int4 vb3 = *reinterpret_cast<const int4*>(Bl + (size_t)(sr + 64) * DIM + k0 + scg);
        __syncthreads();
        *reinterpret_cast<int4*>(&lds[0][sr][scg])      = va0;
        *reinterpret_cast<int4*>(&lds[0][sr + 64][scg]) = va1;
        *reinterpret_cast<int4*>(&lds[1][sr][scg])      = va2;
        *reinterpret_cast<int4*>(&lds[1][sr + 64][scg]) = va3;
        *reinterpret_cast<int4*>(&lds[2][sr][scg])      = vb0;
        *reinterpret_cast<int4*>(&lds[2][sr + 64][scg]) = vb1;
        *reinterpret_cast<int4*>(&lds[3][sr][scg])      = vb2;
        *reinterpret_cast<int4*>(&lds[3][sr + 64][scg]) = vb3;
        __syncthreads();

        short8 ah[4], al4[4], bh4[4], bl4[4];
#pragma unroll
        for (int f = 0; f < 4; ++f) {
            ah[f]  = *reinterpret_cast<const short8*>(&lds[0][wr + f * 16 + fr][fc * 8]);
            al4[f] = *reinterpret_cast<const short8*>(&lds[1][wr + f * 16 + fr][fc * 8]);
            bh4[f] = *reinterpret_cast<const short8*>(&lds[2][wc + f * 16 + fr][fc * 8]);
            bl4[f] = *reinterpret_cast<const short8*>(&lds[3][wc + f * 16 + fr][fc * 8]);
        }
#pragma unroll
        for (int i = 0; i < 4; ++i)
#pragma unroll
            for (int j = 0; j < 4; ++j) {
                acc[i][j] = __builtin_amdgcn_mfma_f32_16x16x32_bf16(ah[i],  bh4[j], acc[i][j], 0, 0, 0);
                acc[i][j] = __builtin_amdgcn_mfma_f32_16x16x32_bf16(ah[i],  bl4[j], acc[i][j], 0, 0, 0);
                acc[i][j] = __builtin_amdgcn_mfma_f32_16x16x32_bf16(al4[i], bh4[j], acc[i][j], 0, 0, 0);
            }
    }

    float* tile = sc + ((size_t)bl * NT2 + t) * 16384;
    const bool diag = (qt == kt);
#pragma unroll
    for (int i = 0; i < 4; ++i)
#pragma unroll
        for (int j = 0; j < 4; ++j)
#pragma unroll
            for (int v = 0; v < 4; ++v) {
                const int row = wr + i * 16 + fc * 4 + v;
                const int col = wc + j * 16 + fr;
                float val = acc[i][j][v] * SCALE;
                if (diag && col >= row) val = -INFINITY;
                tile[row * 128 + col] = val;
            }
}

// ---------------------------------------------------------------------------
// ysem_mfma: C = SCALE * A @ W via bf16 split-3 MFMA; B given transposed.
// ---------------------------------------------------------------------------
__global__ __launch_bounds__(256) void ysem_mfma(const unsigned short* __restrict__ ahi,
                                                 const unsigned short* __restrict__ alo,
                                                 const unsigned short* __restrict__ wthi,
                                                 const unsigned short* __restrict__ wtlo,
                                                 float* __restrict__ C) {
    const int n0 = blockIdx.x * 128;
    const int m0 = blockIdx.y * 128;
    const unsigned short* Ah = ahi + (size_t)m0 * DIM;
    const unsigned short* Al = alo + (size_t)m0 * DIM;
    const unsigned short* Bh = wthi + (size_t)n0 * DIM;
    const unsigned short* Bl = wtlo + (size_t)n0 * DIM;

    __shared__ unsigned short lds[4][128][40];

    const int tid  = threadIdx.x;
    const int lane = tid & 63, wid = tid >> 6;
    const int wr = (wid >> 1) * 64, wc = (wid & 1) * 64;
    const int fr = lane & 15, fc = lane >> 4;
    const int sr  = tid >> 2;
    const int scg = (tid & 3) * 8;

    f32x4 acc[4][4];
    const f32x4 zz = {0.f, 0.f, 0.f, 0.f};
#pragma unroll
    for (int i = 0; i < 4; ++i)
#pragma unroll
        for (int j = 0; j < 4; ++j) acc[i][j] = zz;

    for (int k0 = 0; k0 < DIM; k0 += 32) {
        int4 va0 = *reinterpret_cast<const int4*>(Ah + (size_t)sr * DIM + k0 + scg);
        int4 va1 = *reinterpret_cast<const int4*>(Ah + (size_t)(sr + 64) * DIM + k0 + scg);
        int4 va2 = *reinterpret_cast<const int4*>(Al + (size_t)sr * DIM + k0 + scg);
        int4 va3 = *reinterpret_cast<const int4*>(Al + (size_t)(sr + 64) * DIM + k0 + scg);
        int4 vb0 = *reinterpret_cast<const int4*>(Bh + (size_t)sr * DIM + k0 + scg);
        int4 vb1 = *reinterpret_cast<const int4*>(Bh + (size_t)(sr + 64) * DIM + k0 + scg);
        int4 vb2 = *reinterpret_cast<const int4*>(Bl + (size_t)sr * DIM + k0 + scg);
        int4 vb3 = *reinterpret_cast<const int4*>(Bl + (size_t)(sr + 64) * DIM + k0 + scg);
        __syncthreads();
        *reinterpret_cast<int4*>(&lds[0][sr][scg])      = va0;
        *reinterpret_cast<int4*>(&lds[0][sr + 64][scg]) = va1;
        *reinterpret_cast<int4*>(&lds[1][sr][scg])      = va2;
        *reinterpret_cast<int4*>(&lds[1][sr + 64][scg]) = va3;
        *reinterpret_cast<int4*>(&lds[2][sr][scg])      = vb0;
        *reinterpret_cast<int4*>(&lds[2][sr + 64][scg]) = vb1;
        *reinterpret_cast<int4*>(&lds[3][sr][scg])      = vb2;
        *reinterpret_cast<int4*>(&lds[3][sr + 64][scg]) = vb3;
        __syncthreads();

        short8 ah[4], al4[4], bh4[4], bl4[4];
#pragma unroll
        for (int f = 0; f < 4; ++f) {
            ah[f]  = *reinterpret_cast<const short8*>(&lds[0][wr + f * 16 + fr][fc * 8]);
            al4[f] = *reinterpret_cast<const short8*>(&lds[1][wr + f * 16 + fr][fc * 8]);
            bh4[f] = *reinterpret_cast<const short8*>(&lds[2][wc + f * 16 + fr][fc * 8]);
            bl4[f] = *reinterpret_cast<const short8*>(&lds[3][wc + f * 16 + fr][fc * 8]);
        }
#pragma unroll
        for (int i = 0; i < 4; ++i)
#pragma unroll
            for (int j = 0; j < 4; ++j) {
                acc[i][j] = __builtin_amdgcn_mfma_f32_16x16x32_bf16(ah[i],  bh4[j], acc[i][j], 0, 0, 0);
                acc[i][j] = __builtin_amdgcn_mfma_f32_16x16x32_bf16(ah[i],  bl4[j], acc[i][j], 0, 0, 0);
                acc[i][j] = __builtin_amdgcn_mfma_f32_16x16x32_bf16(al4[i], bh4[j], acc[i][j], 0, 0, 0);
            }
    }

#pragma unroll
    for (int i = 0; i < 4; ++i)
#pragma unroll
        for (int j = 0; j < 4; ++j)
#pragma unroll
            for (int v = 0; v < 4; ++v) {
                const int row = wr + i * 16 + fc * 4 + v;
                const int col = wc + j * 16 + fr;
                C[(size_t)(m0 + row) * DIM + n0 + col] = acc[i][j][v] * SCALE;
            }
}

// ---------------------------------------------------------------------------
// Kernel 3: exact top-64 per row. Radix histogram (valid elements only) +
// parallel suffix-sum bin search + tie ranking + fp64 boundary fixup.
// ---------------------------------------------------------------------------
__device__ __forceinline__ unsigned flipf(float v) {
    unsigned bu = __float_as_uint(v);
    return bu ^ ((unsigned)((int)bu >> 31) | 0x80000000u);
}

__global__ __launch_bounds__(256) void row_topk(const float* __restrict__ hs,
                                                const float* __restrict__ sc,
                                                float* __restrict__ lv,
                                                int* __restrict__ li, int b0) {
    const int bl = blockIdx.x >> 11;
    const int i  = blockIdx.x & 2047;
    const int b  = b0 + bl;
    const int tid = threadIdx.x;

    float* outv = lv + (((size_t)b * SEQT + i) << 6);
    int*   outi = li + (((size_t)b * SEQT + i) << 6);
    const size_t batch_off = (size_t)bl * NT2 * 16384;

    if (i <= KTOP) {
        if (tid < KTOP) {
            float v = 0.f;
            int   ix = 0;
            if (tid < i) {
                v  = sc[batch_off + (size_t)i * 128 + tid];
                ix = tid;
            }
            outv[tid] = v;
            outi[tid] = ix;
        }
        return;
    }

    const int qt = i >> 7, r = i & 127;
    const int nscan = (qt + 1) * 128;
    const size_t rowb = batch_off + ((size_t)(qt * (qt + 1) / 2)) * 16384 + (size_t)r * 128;

    float    ev[8];
    unsigned eu[8];
#pragma unroll
    for (int s = 0; s < 8; ++s) {
        const int j = tid + (s << 8);
        ev[s] = (j < nscan) ? sc[rowb + ((size_t)(j >> 7)) * 16384 + (j & 127)] : -INFINITY;
        eu[s] = flipf(ev[s]);
    }

    __shared__ int hist[2048];
    __shared__ int wtot[4];
    __shared__ int sfxs[257];
    __shared__ int hv[8];
    __shared__ int sB, sM;
    __shared__ int ocnt, ccnt;
    if (tid == 0) { ocnt = 0; ccnt = 0; }
    for (int h = tid; h < 2048; h += 256) hist[h] = 0;
    __syncthreads();
    // histogram: valid (unmasked, in-range) elements only — avoids the
    // same-address atomic storm on bin 0 from -inf padding.
#pragma unroll
    for (int s = 0; s < 8; ++s) {
        const int j = tid + (s << 8);
        if (j < nscan && ev[s] != -INFINITY) atomicAdd(&hist[eu[s] >> 21], 1);
    }
    __syncthreads();

    // per-thread 8-bin group sum, then parallel reverse (suffix) scan
    int part = 0;
#pragma unroll
    for (int h = 0; h < 8; ++h) part += hist[tid * 8 + h];
    const int lane = tid & 63, w = tid >> 6;
    int sfx = part;
#pragma unroll
    for (int off = 1; off < 64; off <<= 1) {
        int o = __shfl_down(sfx, off, 64);
        if (lane + off < 64) sfx += o;
    }
    if (lane == 0) wtot[w] = sfx;
    __syncthreads();
#pragma unroll
    for (int w2 = 0; w2 < 4; ++w2)
        if (w2 > w) sfx += wtot[w2];
    sfxs[tid] = sfx;
    if (tid == 255) sfxs[256] = 0;
    // suffix is non-increasing in tid -> flag set is a prefix; g* = count-1
    const int nflag = __syncthreads_count(sfx >= KTOP);
    const int gs = nflag - 1;
    if (tid < 8) hv[tid] = hist[gs * 8 + tid];
    __syncthreads();
    if (tid == 0) {
        int h0 = hv[0], h1 = hv[1], h2 = hv[2], h3 = hv[3];
        int h4 = hv[4], h5 = hv[5], h6 = hv[6], h7 = hv[7];
        const int hh[8] = {h0, h1, h2, h3, h4, h5, h6, h7};
        int acc = sfxs[gs + 1];
        int B = gs * 8;
        for (int h = 7; h >= 0; --h) {
            if (acc + hh[h] >= KTOP) { B = gs * 8 + h; break; }
            acc += hh[h];
        }
        sB = B;
        sM = acc;   // elements in bins > B  (m < 64)
    }
    __syncthreads();
    const unsigned B = (unsigned)sB;
    const int m = sM;
    const int tn = KTOP - m;

    __shared__ unsigned cu[512];
    __shared__ float    cva[512];
    __shared__ int      cix[512];
    __shared__ float    lsv[64];

    // single merged collect pass: winners (bin > B) straight to slots [0,m);
    // boundary-bin (== B) candidates to the ranking buffer.
#pragma unroll
    for (int s = 0; s < 8; ++s) {
        const int j = tid + (s << 8);
        if (j < nscan && ev[s] != -INFINITY) {
            const unsigned bin = eu[s] >> 21;
            if (bin > B) {
                int p = atomicAdd(&ocnt, 1);
                outv[p] = ev[s];
                outi[p] = j;
                lsv[p]  = ev[s];
            } else if (bin == B) {
                int p = atomicAdd(&ccnt, 1);
                if (p < 512) { cu[p] = eu[s]; cva[p] = ev[s]; cix[p] = j; }
            }
        }
    }
    __syncthreads();
    const int cb = (ccnt < 512) ? ccnt : 512;

    // rank boundary-bin candidates by (u desc, idx asc); ranks distinct
    for (int c = tid; c < cb; c += 256) {
        const unsigned u = cu[c];
        const int ix = cix[c];
        int rk = 0;
        for (int c2 = 0; c2 < cb; ++c2) {
            const unsigned u2 = cu[c2];
            rk += (u2 > u) || (u2 == u && cix[c2] < ix);
        }
        if (rk < tn) { outv[m + rk] = cva[c]; outi[m + rk] = ix; lsv[m + rk] = cva[c]; }
    }

    // ---------------- fp64 boundary fixup ----------------
    __shared__ float  svmin;
    __shared__ int    tcnt;
    __shared__ int    spos[64];
    __shared__ double dval[256];
    __syncthreads();
    if (tid == 0) {
        float mv = lsv[0];
        for (int k = 1; k < KTOP; ++k) mv = fminf(mv, lsv[k]);
        svmin = mv;
        ccnt = 0;
        tcnt = 0;
    }
    __syncthreads();
    const float vmin = svmin;
#pragma unroll
    for (int s = 0; s < 8; ++s) {
        const int j = tid + (s << 8);
        if (j < nscan && fabsf(ev[s] - vmin) <= DELTA) {
            int p = atomicAdd(&ccnt, 1);
            if (p < 256) { cva[p] = ev[s]; cix[p] = j; }
        }
    }
    __syncthreads();
    const int mb = ccnt;
    if (mb < 2 || mb > 256) return;

    if (tid < KTOP && fabsf(lsv[tid] - vmin) <= DELTA) {
        int q = atomicAdd(&tcnt, 1);
        spos[q] = tid;
    }
    __syncthreads();
    const int t = tcnt;

    const int wid = tid >> 6;
    const float* qrow = hs + ((size_t)b * SEQT + i) * DIM;
    for (int c = wid; c < mb; c += 4) {
        const float* krow = hs + ((size_t)b * SEQT + cix[c]) * DIM;
        double acc = 0.0;
        for (int d = lane; d < DIM; d += 64)
            acc += (double)qrow[d] * (double)krow[d];
#pragma unroll
        for (int off = 32; off; off >>= 1) acc += __shfl_xor(acc, off, 64);
        if (lane == 0) dval[c] = acc;
    }
    __syncthreads();

    if (tid < mb) {
        const double dv = dval[tid];
        const int ix = cix[tid];
        int rk = 0;
        for (int c2 = 0; c2 < mb; ++c2)
            rk += (dval[c2] > dv) || (dval[c2] == dv && cix[c2] < ix);
        if (rk < t) {
            const int pp = spos[rk];
            outv[pp] = cva[tid];
            outi[pp] = ix;
        }
    }
}

// ---------------------------------------------------------------------------
// Kernel 4 (levels 1-2): gather y_episodic from bf16-hi rows (L2-resident),
// gate, final output. XCD-batch affinity: batch = (blockIdx%8)>>1.
// ---------------------------------------------------------------------------
__global__ __launch_bounds__(512) void gather_bf16(const unsigned short* __restrict__ hhi,
                                                   const float* __restrict__ lv,
                                                   const int* __restrict__ li,
                                                   float* __restrict__ io) {
    const int tid  = threadIdx.x;
    const int lane = tid & 63;
    const int wid  = tid >> 6;
    const int blk  = blockIdx.x;
    const int xs   = blk & 7;                       // ~XCD slot
    const int b    = xs >> 1;                       // batch per XCD pair
    const int rg   = (blk >> 3) * 2 + (xs & 1);     // 0..255
    const int i    = rg * 8 + wid;                  // row in batch

    const size_t row = (size_t)b * SEQT + i;
    const float4* v4 = reinterpret_cast<const float4*>(lv + (row << 6));
    const int4*   i4 = reinterpret_cast<const int4*>(li + (row << 6));
    const unsigned short* hb = hhi + (size_t)b * SEQT * DIM;
    const int d0 = lane * 8;

    float y[16];
#pragma unroll
    for (int t = 0; t < 16; ++t) y[t] = 0.f;

#pragma unroll 2
    for (int kk = 0; kk < 16; ++kk) {
        const float4 vv = v4[kk];
        const int4   ii = i4[kk];
        const float  vs[4] = {vv.x, vv.y, vv.z, vv.w};
        const int    js[4] = {ii.x, ii.y, ii.z, ii.w};
#pragma unroll
        for (int c = 0; c < 4; ++c) {
            const float v = vs[c];
            const unsigned short* hr = hb + (size_t)js[c] * DIM + d0;
            uint4 w0 = *reinterpret_cast<const uint4*>(hr);
            uint4 w1 = *reinterpret_cast<const uint4*>(hr + 512);
            const unsigned wa[8] = {w0.x, w0.y, w0.z, w0.w, w1.x, w1.y, w1.z, w1.w};
#pragma unroll
            for (int e = 0; e < 8; ++e) {
                float flo = __uint_as_float(wa[e] << 16);
                float fhi = __uint_as_float(wa[e] & 0xffff0000u);
                y[2 * e + 0] += v * flo;
                y[2 * e + 1] += v * fhi;
            }
        }
    }

    float* iorow = io + row * DIM;
    float4 s0 = *reinterpret_cast<const float4*>(iorow + d0);
    float4 s1 = *reinterpret_cast<const float4*>(iorow + d0 + 4);
    float4 s2 = *reinterpret_cast<const float4*>(iorow + 512 + d0);
    float4 s3 = *reinterpret_cast<const float4*>(iorow + 512 + d0 + 4);
    const float ss[16] = {s0.x, s0.y, s0.z, s0.w, s1.x, s1.y, s1.z, s1.w,
                          s2.x, s2.y, s2.z, s2.w, s3.x, s3.y, s3.z, s3.w};
    float p = 0.f;
#pragma unroll
    for (int t = 0; t < 16; ++t) p += y[t] * ss[t];
#pragma unroll
    for (int off = 32; off; off >>= 1) p += __shfl_xor(p, off, 64);
    const float g  = 1.f / (1.f + __expf(-p));
    const float og = 1.f - g;
    float o[16];
#pragma unroll
    for (int t = 0; t < 16; ++t) o[t] = g * y[t] + og * ss[t];
    *reinterpret_cast<float4*>(iorow + d0)           = *reinterpret_cast<float4*>(&o[0]);
    *reinterpret_cast<float4*>(iorow + d0 + 4)       = *reinterpret_cast<float4*>(&o[4]);
    *reinterpret_cast<float4*>(iorow + 512 + d0)     = *reinterpret_cast<float4*>(&o[8]);
    *reinterpret_cast<float4*>(iorow + 512 + d0 + 4) = *reinterpret_cast<float4*>(&o[12]);
}

// ---------------------------------------------------------------------------
// Kernel 4 (level-3 fallback): fp32 gather (hhi holds only one batch there).
// ---------------------------------------------------------------------------
__global__ __launch_bounds__(512) void merge_gather(const float* __restrict__ hs,
                                                    const float* __restrict__ lv,
                                                    const int* __restrict__ li,
                                                    float* __restrict__ io) {
    const int tid  = threadIdx.x;
    const int lane = tid & 63;
    const int wid  = tid >> 6;
    const int b    = blockIdx.x >> 7;
    const int r0   = (blockIdx.x & 127) * 16;
    const float* hb = hs + (size_t)b * SEQT * DIM;
    const int dofs = lane * 4;

    for (int rr = wid; rr < 16; rr += 8) {
        const int i = r0 + rr;
        const size_t row = (size_t)b * SEQT + i;
        const float4* v4 = reinterpret_cast<const float4*>(lv + (row << 6));
        const int4*   i4 = reinterpret_cast<const int4*>(li + (row << 6));

        float4 y0 = {0.f, 0.f, 0.f, 0.f}, y1 = y0, y2 = y0, y3 = y0;
#pragma unroll 4
        for (int kk = 0; kk < 16; ++kk) {
            const float4 vv = v4[kk];
            const int4   ii = i4[kk];
            const float  vs[4] = {vv.x, vv.y, vv.z, vv.w};
            const int    js[4] = {ii.x, ii.y, ii.z, ii.w};
#pragma unroll
            for (int c = 0; c < 4; ++c) {
                const float v = vs[c];
                const float* hr = hb + (size_t)js[c] * DIM + dofs;
                float4 a = *reinterpret_cast<const float4*>(hr);
                float4 cc = *reinterpret_cast<const float4*>(hr + 256);
                float4 d = *reinterpret_cast<const float4*>(hr + 512);
                float4 e = *reinterpret_cast<const float4*>(hr + 768);
                y0.x += v * a.x;  y0.y += v * a.y;  y0.z += v * a.z;  y0.w += v * a.w;
                y1.x += v * cc.x; y1.y += v * cc.y; y1.z += v * cc.z; y1.w += v * cc.w;
                y2.x += v * d.x;  y2.y += v * d.y;  y2.z += v * d.z;  y2.w += v * d.w;
                y3.x += v * e.x;  y3.y += v * e.y;  y3.z += v * e.z;  y3.w += v * e.w;
            }
        }

        float* iorow = io + row * DIM + dofs;
        float4 s0 = *reinterpret_cast<const float4*>(iorow);
        float4 s1 = *reinterpret_cast<const float4*>(iorow + 256);
        float4 s2 = *reinterpret_cast<const float4*>(iorow + 512);
        float4 s3 = *reinterpret_cast<const float4*>(iorow + 768);
        float p = y0.x * s0.x + y0.y * s0.y + y0.z * s0.z + y0.w * s0.w
                + y1.x * s1.x + y1.y * s1.y + y1.z * s1.z + y1.w * s1.w
                + y2.x * s2.x + y2.y * s2.y + y2.z * s2.z + y2.w * s2.w
                + y3.x * s3.x + y3.y * s3.y + y3.z * s3.z + y3.w * s3.w;
#pragma unroll
        for (int off = 32; off; off >>= 1) p += __shfl_xor(p, off, 64);
        const float g  = 1.f / (1.f + __expf(-p));
        const float og = 1.f - g;
        float4 o0, o1, o2, o3;
        o0.x = g * y0.x + og * s0.x; o0.y = g * y0.y + og * s0.y;
        o0.z = g * y0.z + og * s0.z; o0.w = g * y0.w + og * s0.w;
        o1.x = g * y1.x + og * s1.x; o1.y = g * y1.y + og * s1.y;
        o1.z = g * y1.z + og * s1.z; o1.w = g * y1.w + og * s1.w;
        o2.x = g * y2.x + og * s2.x; o2.y = g * y2.y + og * s2.y;
        o2.z = g * y2.z + og * s2.z; o2.w = g * y2.w + og * s2.w;
        o3.x = g * y3.x + og * s3.x; o3.y = g * y3.y + og * s3.y;
        o3.z = g * y3.z + og * s3.z; o3.w = g * y3.w + og * s3.w;
        *reinterpret_cast<float4*>(iorow)       = o0;
        *reinterpret_cast<float4*>(iorow + 256) = o1;
        *reinterpret_cast<float4*>(iorow + 512) = o2;
        *reinterpret_cast<float4*>(iorow + 768) = o3;
    }
}

// ---------------------------------------------------------------------------
extern "C" void kernel_launch(void* const* d_in, const int* in_sizes, int n_in,
                              void* d_out, int out_size, void* d_ws, size_t ws_size,
                              hipStream_t stream) {
    const float* hs = (const float*)d_in[0];
    const float* W  = (const float*)d_in[1];
    float* out = (float*)d_out;

    const size_t Hfull  = (size_t)NB * SEQT * DIM;     // 8388608
    const size_t Hb     = (size_t)SEQT * DIM;          // 2097152
    const size_t Wn     = (size_t)DIM * DIM;           // 1048576
    const size_t Lf     = (size_t)NB * SEQT * KTOP;    // 524288
    const size_t SCfull = (size_t)NB * NT2 * 16384;
    const size_t SCb    = (size_t)NT2 * 16384;

    auto need = [&](size_t H, size_t SC) {
        return (2 * H + 2 * Wn) * sizeof(unsigned short) + Lf * 8 + SC * 4;
    };
    int level = (need(Hfull, SCfull) <= ws_size) ? 1
              : (need(Hfull, SCb) <= ws_size)    ? 2 : 3;

    const size_t H  = (level == 3) ? Hb : Hfull;

    unsigned short* hhi  = (unsigned short*)d_ws;
    unsigned short* hlo  = hhi + H;
    unsigned short* wthi = hlo + H;
    unsigned short* wtlo = wthi + Wn;
    float* lv = (float*)(wtlo + Wn);
    int*   li = (int*)(lv + Lf);
    float* sc = (float*)(li + Lf);

    wtrans_split<<<dim3(16, 16), dim3(256), 0, stream>>>(W, wthi, wtlo);

    if (level == 1) {
        split_bf16<<<dim3(2048), dim3(256), 0, stream>>>(hs, hhi, hlo, (int)(Hfull / 4));
        score_mfma<<<dim3(NB * NT2), dim3(256), 0, stream>>>(hhi, hlo, sc, 0);
        row_topk<<<dim3(NB * SEQT), dim3(256), 0, stream>>>(hs, sc, lv, li, 0);
        ysem_mfma<<<dim3(DIM / 128, (NB * SEQT) / 128), dim3(256), 0, stream>>>(hhi, hlo, wthi, wtlo, out);
        gather_bf16<<<dim3(1024), dim3(512), 0, stream>>>(hhi, lv, li, out);
    } else if (level == 2) {
        split_bf16<<<dim3(2048), dim3(256), 0, stream>>>(hs, hhi, hlo, (int)(Hfull / 4));
        for (int b = 0; b < NB; ++b) {
            score_mfma<<<dim3(NT2), dim3(256), 0, stream>>>(hhi, hlo, sc, b);
            row_topk<<<dim3(SEQT), dim3(256), 0, stream>>>(hs, sc, lv, li, b);
        }
        ysem_mfma<<<dim3(DIM / 128, (NB * SEQT) / 128), dim3(256), 0, stream>>>(hhi, hlo, wthi, wtlo, out);
        gather_bf16<<<dim3(1024), dim3(512), 0, stream>>>(hhi, lv, li, out);
    } else {
        for (int b = 0; b < NB; ++b) {
            split_bf16<<<dim3(512), dim3(256), 0, stream>>>(hs + (size_t)b * Hb, hhi, hlo, (int)(Hb / 4));
            score_mfma<<<dim3(NT2), dim3(256), 0, stream>>>(hhi, hlo, sc, 0);
            row_topk<<<dim3(SEQT), dim3(256), 0, stream>>>(hs, sc, lv, li, b);
            ysem_mfma<<<dim3(DIM / 128, SEQT / 128), dim3(256), 0, stream>>>(hhi, hlo, wthi, wtlo, out + (size_t)b * Hb);
        }
        merge_gather<<<dim3(NB * 128), dim3(512), 0, stream>>>(hs, lv, li, out);
    }
}